// Round 13
// baseline (438.804 us; speedup 1.0000x reference)
//
#include <hip/hip_runtime.h>
#include <hip/hip_bf16.h>

#define E_EDGES 131072
#define NNODES  8192
#define NB      16384   // N_NODES * BATCH rows
#define HID     256
#define EDIM    64
#define MLPH    512
#define OUTD    128
#define NIT     3
#define RB      64      // rows per node_update block

typedef short s16x4 __attribute__((ext_vector_type(4)));
typedef short s16x8 __attribute__((ext_vector_type(8)));
typedef float f32x4 __attribute__((ext_vector_type(4)));
typedef float f32x2 __attribute__((ext_vector_type(2)));
typedef unsigned int u32x4 __attribute__((ext_vector_type(4)));

__device__ __forceinline__ short f2bf(float f){
  unsigned int x = __builtin_bit_cast(unsigned int, f);
  x += 0x7fffu + ((x >> 16) & 1u);          // RNE
  return (short)(x >> 16);
}
__device__ __forceinline__ float bf2f(short s){
  unsigned int x = ((unsigned int)(unsigned short)s) << 16;
  return __builtin_bit_cast(float, x);
}
__device__ __forceinline__ void gload_lds16(const void* g, void* l){
  __builtin_amdgcn_global_load_lds(
      (const __attribute__((address_space(1))) void*)g,
      (__attribute__((address_space(3))) void*)l, 16, 0, 0);
}
#define MFMA16(a,b,c) __builtin_amdgcn_mfma_f32_16x16x32_bf16((a),(b),(c),0,0,0)

// ---------------- fp8 (e4m3-style) encode/decode ----------------
#if defined(__has_builtin)
#if __has_builtin(__builtin_amdgcn_cvt_pk_f32_fp8) && __has_builtin(__builtin_amdgcn_cvt_pk_fp8_f32)
#define FP8_HW 1
#endif
#endif
#ifndef FP8_HW
#define FP8_HW 0
#endif

__device__ __forceinline__ unsigned char enc_fp8_sw(float f){
  unsigned int b = __builtin_bit_cast(unsigned int, f);
  unsigned int s = (b >> 24) & 0x80u;
  float a = fabsf(f);
  if (a >= 448.f) return (unsigned char)(s | 0x7e);       // clamp to 448
  if (a < 0.015625f){                                      // denorm: m*2^-9
    int q = (int)rintf(a * 512.f);                         // 0..8
    return (unsigned char)(s | (unsigned int)q);           // q==8 -> e=1,m=0
  }
  unsigned int e32  = (b >> 23) & 0xff;
  unsigned int mant = b & 0x7fffff;
  unsigned int rnd  = mant + 0x7ffff + ((mant >> 20) & 1); // RNE at bit 20
  unsigned int e8   = e32 - 120 + (rnd >> 23);
  unsigned int m3   = (rnd >> 20) & 7;
  if (e8 >= 16) return (unsigned char)(s | 0x7e);
  return (unsigned char)(s | (e8 << 3) | m3);
}
__device__ __forceinline__ float dec_fp8_sw(unsigned int v){
  unsigned int s = (v >> 7) & 1, e = (v >> 3) & 15, m = v & 7;
  float r;
  if (e == 0) r = (float)m * 0.001953125f;                 // m * 2^-9
  else        r = __builtin_bit_cast(float, ((e + 120u) << 23) | (m << 20));
  return s ? -r : r;
}
__device__ __forceinline__ unsigned char enc_fp8(float f){
#if FP8_HW
  unsigned int pk = (unsigned int)__builtin_amdgcn_cvt_pk_fp8_f32(f, f, 0, false);
  return (unsigned char)(pk & 0xff);
#else
  return enc_fp8_sw(f);
#endif
}
__device__ __forceinline__ void dec_fp8x4(unsigned int ev, float& e0, float& e1,
                                          float& e2, float& e3){
#if FP8_HW
  f32x2 lo = __builtin_amdgcn_cvt_pk_f32_fp8((int)ev, false);
  f32x2 hi = __builtin_amdgcn_cvt_pk_f32_fp8((int)ev, true);
  e0 = lo[0]; e1 = lo[1]; e2 = hi[0]; e3 = hi[1];
#else
  e0 = dec_fp8_sw(ev & 0xff); e1 = dec_fp8_sw((ev >> 8) & 0xff);
  e2 = dec_fp8_sw((ev >> 16) & 0xff); e3 = dec_fp8_sw(ev >> 24);
#endif
}

// ===========================================================================
// e1_gemm v3 (R12, unchanged) — runs ONCE. Block = 128 CSR rows; loops 4
// column panels in-block; swapped-operand MFMA -> LDS tile -> coalesced 16B.
// ===========================================================================
__global__ __launch_bounds__(256, 3)
void e1_gemm(const float* __restrict__ ef, const short* __restrict__ BtE,
             unsigned char* __restrict__ E1, const float* __restrict__ b1,
             const int* __restrict__ ceid)
{
  __shared__ __align__(16) short As[128 * 64];
  __shared__ __align__(16) short Bs[128 * 64];
  __shared__ __align__(16) unsigned char Ts[128 * 128];

  const int t  = threadIdx.x;
  const int w  = t >> 6, l = t & 63;
  const int lr = l & 15, lg = l >> 4;
  const int wr = w >> 1, wc = w & 1;
  const int browbase = blockIdx.x * 128;
  const int srow = t >> 3;
  const int scol = (t & 7) * 8;

#pragma unroll
  for (int i = 0; i < 4; ++i){
    int R = browbase + srow + i * 32;
    int e = ceid[R >> 1];
    const float* ap = ef + ((size_t)e * 2 + (R & 1)) * EDIM + scol;
    f32x4 f0 = *(const f32x4*)ap;
    f32x4 f1 = *(const f32x4*)(ap + 4);
    s16x8 o;
    o[0]=f2bf(f0[0]); o[1]=f2bf(f0[1]); o[2]=f2bf(f0[2]); o[3]=f2bf(f0[3]);
    o[4]=f2bf(f1[0]); o[5]=f2bf(f1[1]); o[6]=f2bf(f1[2]); o[7]=f2bf(f1[3]);
    int row = srow + i * 32;
    *(s16x8*)(As + row * 64 + (scol ^ ((row & 7) << 3))) = o;
  }

  for (int pn = 0; pn < 4; ++pn){
#pragma unroll
    for (int i = 0; i < 4; ++i)
      gload_lds16(BtE + (size_t)(pn * 128 + srow + i * 32) * 64 + scol,
                  (char*)Bs + w * 1024 + i * 4096);
    __syncthreads();

    f32x4 acc[4][4];
#pragma unroll
    for (int mf = 0; mf < 4; ++mf)
#pragma unroll
      for (int e2 = 0; e2 < 4; ++e2) acc[mf][e2] = (f32x4){0.f,0.f,0.f,0.f};

#pragma unroll
    for (int kk = 0; kk < 2; ++kk){
      s16x8 a[4], b[4];
#pragma unroll
      for (int e2 = 0; e2 < 4; ++e2){
        int ar = wr*64 + e2*16 + lr;
        a[e2] = *(const s16x8*)(As + ar * 64 + ((kk*32 + lg*8) ^ ((ar & 7) << 3)));
      }
#pragma unroll
      for (int mf = 0; mf < 4; ++mf){
        int br = wc*64 + mf*16 + lr;
        b[mf] = *(const s16x8*)(Bs + br * 64 + ((kk*32 + lg*8) ^ ((br & 7) << 3)));
      }
#pragma unroll
      for (int mf = 0; mf < 4; ++mf)
#pragma unroll
        for (int e2 = 0; e2 < 4; ++e2)
          acc[mf][e2] = MFMA16(b[mf], a[e2], acc[mf][e2]);   // swapped
    }

#pragma unroll
    for (int mf = 0; mf < 4; ++mf){
      int mloc = wc*64 + mf*16 + lg*4;
      f32x4 bv = *(const f32x4*)(b1 + pn*128 + mloc);
      int u = mloc >> 2;
      int usw_hi = (u >> 2), ulo = (u & 3) << 2;
#pragma unroll
      for (int e2 = 0; e2 < 4; ++e2){
        int erow = wr*64 + e2*16 + lr;
        unsigned int pk = (unsigned int)enc_fp8(acc[mf][e2][0] + bv[0])
                        | ((unsigned int)enc_fp8(acc[mf][e2][1] + bv[1]) << 8)
                        | ((unsigned int)enc_fp8(acc[mf][e2][2] + bv[2]) << 16)
                        | ((unsigned int)enc_fp8(acc[mf][e2][3] + bv[3]) << 24);
        *(unsigned int*)(Ts + erow * 128 + ((usw_hi ^ (erow & 7)) << 4) + ulo) = pk;
      }
    }
    __syncthreads();

    {
      int rr = t >> 1, hh = t & 1;
#pragma unroll
      for (int q = 0; q < 4; ++q){
        int u16 = q * 2 + hh;
        u32x4 v = *(const u32x4*)(Ts + rr * 128 + ((u16 ^ (rr & 7)) << 4));
        *(u32x4*)(E1 + (size_t)(browbase + rr) * 512 + pn * 128 + u16 * 16) = v;
      }
    }
  }
}

// ===========================================================================
// edge_kernel (unchanged): S[n] = sum_{e: dst=n} relu(P1[n]+P2[src]+E1[e])
// ===========================================================================
template<bool USE_P>
__global__ __launch_bounds__(256)
void edge_kernel(const short* __restrict__ P, const unsigned char* __restrict__ E1,
                 const int* __restrict__ csr_src, const int* __restrict__ row_start,
                 short* __restrict__ S)
{
  const int n = blockIdx.x;
  const int t = threadIdx.x;
  const int b = t >> 7;
  const int j = (t & 127) << 2;
  const int ps = row_start[n], pe = row_start[n + 1];

  float p10 = 0.f, p11 = 0.f, p12 = 0.f, p13 = 0.f;
  if (USE_P){
    s16x4 t1 = *(const s16x4*)(P + (size_t)(n * 2 + b) * 1024 + j);
    p10 = bf2f(t1[0]); p11 = bf2f(t1[1]); p12 = bf2f(t1[2]); p13 = bf2f(t1[3]);
  }
  float a0 = 0.f, a1 = 0.f, a2 = 0.f, a3 = 0.f;
  for (int p = ps; p < pe; ++p){
    unsigned int ev = *(const unsigned int*)(E1 + ((size_t)p * 2 + b) * 512 + j);
    float e0, e1, e2, e3;
    dec_fp8x4(ev, e0, e1, e2, e3);
    float x0 = p10 + e0, x1 = p11 + e1, x2 = p12 + e2, x3 = p13 + e3;
    if (USE_P){
      int src = csr_src[p];
      s16x4 v2 = *(const s16x4*)(P + (size_t)(src * 2 + b) * 1024 + 512 + j);
      x0 += bf2f(v2[0]); x1 += bf2f(v2[1]); x2 += bf2f(v2[2]); x3 += bf2f(v2[3]);
    }
    a0 += fmaxf(x0, 0.f); a1 += fmaxf(x1, 0.f);
    a2 += fmaxf(x2, 0.f); a3 += fmaxf(x3, 0.f);
  }
  s16x4 o; o[0] = f2bf(a0); o[1] = f2bf(a1); o[2] = f2bf(a2); o[3] = f2bf(a3);
  *(s16x4*)(S + (size_t)(n * 2 + b) * 512 + j) = o;
}

// ===========================================================================
// node_update v5 — RB=64 (256 blocks): each staged weight chunk feeds 2 row
// frags/wave -> weight L2 traffic and barrier-pairs-per-row both HALVE.
// 512 thr (8 waves = 2 row-halves x 4 col-quarters), LDS 104KB -> 1 blk/CU.
// PH0: K=256 gates; PH2: in-LDS readout.
// ===========================================================================
template<int PH>
__global__ __launch_bounds__(512, 2)
void node_update(const short* __restrict__ S, short* __restrict__ Pout,
                 float* __restrict__ m, float* __restrict__ h,
                 float* __restrict__ g,
                 const short* __restrict__ BtW2, const short* __restrict__ BtRZ,
                 const short* __restrict__ BtHW, const short* __restrict__ BtP,
                 const int* __restrict__ deg, const float* __restrict__ b2,
                 const float* __restrict__ br, const float* __restrict__ bz,
                 const float* __restrict__ bh)
{
  __shared__ __align__(16) char lds[106496];
  short* As = (short*)lds;              // [64][64]   8KB
  short* Bs = (short*)(lds + 8192);     // [256][64] 32KB
  short* Ms = (short*)(lds + 40960);    // [64][256] 32KB
  short* Xs = (short*)(lds + 73728);    // [64][256] 32KB
  float* Hf = (float*)lds;              // [64][256] 64KB overlay (PH2 only)

  const int tid = threadIdx.x;
  const int w = tid >> 6, l = tid & 63;
  const int lr = l & 15, lg = l >> 4;
  const int wq = w >> 2, wc = w & 3;    // row-half, col-quarter
  const int rb = wq * 32;
  const int grow0 = blockIdx.x * RB;

  auto stageB = [&](const short* Bt, int K, int pcol0, int k0){
#pragma unroll
    for (int i = 0; i < 4; ++i){
      int u = i * 512 + tid;
      int row = u >> 3, uc = u & 7;
      const short* gp = Bt + (size_t)(pcol0 + row) * K + k0 + ((uc ^ (row & 7)) << 3);
      gload_lds16(gp, (char*)Bs + i * 8192 + w * 1024);
    }
  };
  auto stageA_S = [&](int k0){
    int row = tid >> 3, uc = tid & 7;
    const short* gp = S + (size_t)(grow0 + row) * 512 + k0 + ((uc ^ (row & 7)) << 3);
    gload_lds16(gp, (char*)As + w * 1024);
  };
  auto rdA64 = [&](int row, int colel){ return row * 64 + (colel ^ ((row & 7) << 3)); };
  auto rd256 = [&](int row, int colel){ return row * 256 + (colel ^ ((row & 7) << 3)); };

  // ---- h into regs, acc init = m + deg*b2; Xs <- bf16(h) ----
  f32x4 hv[2][4], acc[2][4];
#pragma unroll
  for (int i = 0; i < 2; ++i)
#pragma unroll
    for (int j = 0; j < 4; ++j)
#pragma unroll
      for (int r = 0; r < 4; ++r){
        int rl = rb + i*16 + lg*4 + r, colp = wc*64 + j*16 + lr;
        size_t gi = (size_t)(grow0 + rl) * 256 + colp;
        float base = (float)deg[(grow0 + rl) >> 1] * b2[colp];
        if (PH > 0){ base += m[gi]; hv[i][j][r] = h[gi]; }
        else hv[i][j][r] = 0.f;
        acc[i][j][r] = base;
      }
  if (PH > 0){
#pragma unroll
    for (int i = 0; i < 2; ++i)
#pragma unroll
      for (int j = 0; j < 4; ++j)
#pragma unroll
        for (int r = 0; r < 4; ++r){
          int rl = rb + i*16 + lg*4 + r, colp = wc*64 + j*16 + lr;
          Xs[rd256(rl, colp)] = f2bf(hv[i][j][r]);
        }
  }

  // ---- Phase A: acc += S @ W2 (K=512, 8 staged chunks) ----
  for (int c = 0; c < 8; ++c){
    __syncthreads();
    stageA_S(c * 64);
    stageB(BtW2, 512, 0, c * 64);
    __syncthreads();
#pragma unroll
    for (int kk = 0; kk < 2; ++kk){
      s16x8 a0 = *(const s16x8*)(As + rdA64(rb + lr,      kk*32 + lg*8));
      s16x8 a1 = *(const s16x8*)(As + rdA64(rb + 16 + lr, kk*32 + lg*8));
#pragma unroll
      for (int j = 0; j < 4; ++j){
        s16x8 bb = *(const s16x8*)(Bs + rdA64(wc*64 + j*16 + lr, kk*32 + lg*8));
        acc[0][j] = MFMA16(a0, bb, acc[0][j]);
        acc[1][j] = MFMA16(a1, bb, acc[1][j]);
      }
    }
  }
#pragma unroll
  for (int i = 0; i < 2; ++i)
#pragma unroll
    for (int j = 0; j < 4; ++j)
#pragma unroll
      for (int r = 0; r < 4; ++r){
        int rl = rb + i*16 + lg*4 + r, colp = wc*64 + j*16 + lr;
        float v = acc[i][j][r];
        if (PH < 2) m[(size_t)(grow0 + rl) * 256 + colp] = v;
        Ms[rd256(rl, colp)] = f2bf(v);
      }

  const int NC = (PH > 0) ? 8 : 4;       // gate K-chunks (PH0: U-half is zero)

  // ---- Phase B: Gr ----
  f32x4 Gr[2][4], Gz[2][4];
#pragma unroll
  for (int i = 0; i < 2; ++i)
#pragma unroll
    for (int j = 0; j < 4; ++j){ Gr[i][j] = (f32x4){0.f,0.f,0.f,0.f}; Gz[i][j] = (f32x4){0.f,0.f,0.f,0.f}; }

  for (int c = 0; c < NC; ++c){
    __syncthreads();
    stageB(BtRZ, 512, 0, c * 64);
    __syncthreads();
    const short* Ab = (c < 4) ? Ms : Xs;
    int kb = (c & 3) * 64;
#pragma unroll
    for (int kk = 0; kk < 2; ++kk){
      s16x8 a0 = *(const s16x8*)(Ab + rd256(rb + lr,      kb + kk*32 + lg*8));
      s16x8 a1 = *(const s16x8*)(Ab + rd256(rb + 16 + lr, kb + kk*32 + lg*8));
#pragma unroll
      for (int j = 0; j < 4; ++j){
        s16x8 bb = *(const s16x8*)(Bs + rdA64(wc*64 + j*16 + lr, kk*32 + lg*8));
        Gr[0][j] = MFMA16(a0, bb, Gr[0][j]);
        Gr[1][j] = MFMA16(a1, bb, Gr[1][j]);
      }
    }
  }
  // ---- Phase C: Gz ----
  for (int c = 0; c < NC; ++c){
    __syncthreads();
    stageB(BtRZ, 512, 256, c * 64);
    __syncthreads();
    const short* Ab = (c < 4) ? Ms : Xs;
    int kb = (c & 3) * 64;
#pragma unroll
    for (int kk = 0; kk < 2; ++kk){
      s16x8 a0 = *(const s16x8*)(Ab + rd256(rb + lr,      kb + kk*32 + lg*8));
      s16x8 a1 = *(const s16x8*)(Ab + rd256(rb + 16 + lr, kb + kk*32 + lg*8));
#pragma unroll
      for (int j = 0; j < 4; ++j){
        s16x8 bb = *(const s16x8*)(Bs + rdA64(wc*64 + j*16 + lr, kk*32 + lg*8));
        Gz[0][j] = MFMA16(a0, bb, Gz[0][j]);
        Gz[1][j] = MFMA16(a1, bb, Gz[1][j]);
      }
    }
  }

  // ---- e1: r, z; Xs <- bf16(r*h) ----
  f32x4 zz[2][4];
#pragma unroll
  for (int i = 0; i < 2; ++i)
#pragma unroll
    for (int j = 0; j < 4; ++j)
#pragma unroll
      for (int r = 0; r < 4; ++r){
        int colp = wc*64 + j*16 + lr;
        zz[i][j][r] = 1.f / (1.f + __expf(-(Gz[i][j][r] + bz[colp])));
      }
  if (PH > 0){
    __syncthreads();                     // B/C's Xs(hb) reads done
#pragma unroll
    for (int i = 0; i < 2; ++i)
#pragma unroll
      for (int j = 0; j < 4; ++j)
#pragma unroll
        for (int r = 0; r < 4; ++r){
          int rl = rb + i*16 + lg*4 + r, colp = wc*64 + j*16 + lr;
          float rr = 1.f / (1.f + __expf(-(Gr[i][j][r] + br[colp])));
          Xs[rd256(rl, colp)] = f2bf(rr * hv[i][j][r]);
        }
    __syncthreads();                     // Xs(rh) visible
  }

  // ---- Phase D: Gw = [m|rh] @ BtHW ----
  f32x4 Gw[2][4];
#pragma unroll
  for (int i = 0; i < 2; ++i)
#pragma unroll
    for (int j = 0; j < 4; ++j) Gw[i][j] = (f32x4){0.f,0.f,0.f,0.f};
  for (int c = 0; c < NC; ++c){
    __syncthreads();
    stageB(BtHW, 512, 0, c * 64);
    __syncthreads();
    const short* Ab = (c < 4) ? Ms : Xs;
    int kb = (c & 3) * 64;
#pragma unroll
    for (int kk = 0; kk < 2; ++kk){
      s16x8 a0 = *(const s16x8*)(Ab + rd256(rb + lr,      kb + kk*32 + lg*8));
      s16x8 a1 = *(const s16x8*)(Ab + rd256(rb + 16 + lr, kb + kk*32 + lg*8));
#pragma unroll
      for (int j = 0; j < 4; ++j){
        s16x8 bb = *(const s16x8*)(Bs + rdA64(wc*64 + j*16 + lr, kk*32 + lg*8));
        Gw[0][j] = MFMA16(a0, bb, Gw[0][j]);
        Gw[1][j] = MFMA16(a1, bb, Gw[1][j]);
      }
    }
  }

  // ---- e2: h' ----
  __syncthreads();                       // D's Ms/Xs reads done
#pragma unroll
  for (int i = 0; i < 2; ++i)
#pragma unroll
    for (int j = 0; j < 4; ++j)
#pragma unroll
      for (int r = 0; r < 4; ++r){
        int rl = rb + i*16 + lg*4 + r, colp = wc*64 + j*16 + lr;
        float ht = tanhf(Gw[i][j][r] + bh[colp]);
        float z  = zz[i][j][r];
        float hn = (1.f - z) * hv[i][j][r] + z * ht;
        if (PH < 2){
          h[(size_t)(grow0 + rl) * 256 + colp] = hn;
          Ms[rd256(rl, colp)] = f2bf(hn);
        } else {
          Hf[rl * 256 + colp] = hn;
        }
      }
  __syncthreads();                       // Ms(h') / Hf visible

  if (PH < 2){
    // ---- Phase E: P = h' @ BtP, 4 panels of 256 cols ----
    for (int pn = 0; pn < 4; ++pn){
      f32x4 pa0[4], pa1[4];
#pragma unroll
      for (int j = 0; j < 4; ++j){ pa0[j] = (f32x4){0.f,0.f,0.f,0.f}; pa1[j] = (f32x4){0.f,0.f,0.f,0.f}; }
      for (int c = 0; c < 4; ++c){
        __syncthreads();
        stageB(BtP, 256, pn * 256, c * 64);
        __syncthreads();
#pragma unroll
        for (int kk = 0; kk < 2; ++kk){
          s16x8 a0 = *(const s16x8*)(Ms + rd256(rb + lr,      c*64 + kk*32 + lg*8));
          s16x8 a1 = *(const s16x8*)(Ms + rd256(rb + 16 + lr, c*64 + kk*32 + lg*8));
#pragma unroll
          for (int j = 0; j < 4; ++j){
            s16x8 bb = *(const s16x8*)(Bs + rdA64(wc*64 + j*16 + lr, kk*32 + lg*8));
            pa0[j] = MFMA16(a0, bb, pa0[j]);
            pa1[j] = MFMA16(a1, bb, pa1[j]);
          }
        }
      }
#pragma unroll
      for (int j = 0; j < 4; ++j)
#pragma unroll
        for (int r = 0; r < 4; ++r){
          int colp = wc*64 + j*16 + lr;
          Pout[(size_t)(grow0 + rb + lg*4 + r)      * 1024 + pn*256 + colp] = f2bf(pa0[j][r]);
          Pout[(size_t)(grow0 + rb + 16 + lg*4 + r) * 1024 + pn*256 + colp] = f2bf(pa1[j][r]);
        }
    }
  } else {
    // ---- readout partial over the block's 64 rows ----
    int col = tid & 255, pb = (tid >> 8) & 1;
    float s = 0.f;
#pragma unroll
    for (int rr = 0; rr < 32; ++rr)
      s += Hf[(2*rr + pb) * 256 + col];
    atomicAdd(&g[pb * 256 + col], s);
  }
}

// ------------------------------- CSR build ---------------------------------
__global__ void count_kernel(const int* __restrict__ edst, int* __restrict__ counts){
  int e = blockIdx.x * 256 + threadIdx.x;
  if (e < E_EDGES) atomicAdd(&counts[edst[e]], 1);
}
__global__ void scan_kernel(const int* __restrict__ counts, int* __restrict__ row_start,
                            int* __restrict__ cursor){
  __shared__ int sums[1024];
  int t = threadIdx.x;
  int base = t * 8;
  int loc[8]; int s = 0;
#pragma unroll
  for (int i = 0; i < 8; ++i){ loc[i] = s; s += counts[base + i]; }
  sums[t] = s;
  __syncthreads();
  for (int o = 1; o < 1024; o <<= 1){
    int v = sums[t];
    int u = (t >= o) ? sums[t - o] : 0;
    __syncthreads();
    sums[t] = v + u;
    __syncthreads();
  }
  int excl = (t == 0) ? 0 : sums[t - 1];
#pragma unroll
  for (int i = 0; i < 8; ++i){ int v = excl + loc[i]; row_start[base + i] = v; cursor[base + i] = v; }
  if (t == 1023) row_start[NNODES] = sums[1023];
}
__global__ void fill_kernel(const int* __restrict__ edst, const int* __restrict__ esrc,
                            int* __restrict__ cursor, int* __restrict__ csr_eid,
                            int* __restrict__ csr_src){
  int e = blockIdx.x * 256 + threadIdx.x;
  if (e < E_EDGES){
    int pos = atomicAdd(&cursor[edst[e]], 1);
    csr_eid[pos] = e;
    csr_src[pos] = esrc[e];
  }
}

// --------------------------- weight repacking ------------------------------
// BtP [1024][256], BtE [512][64] PRE-SWIZZLED, BtW2 [256][512],
// BtRZ [512][512] (cols r|z, K = W|U), BtHW [256][512] (K = Wh|Uh)
__global__ void prep_weights(const float* __restrict__ W1, const float* __restrict__ W2,
                             const float* __restrict__ Wr, const float* __restrict__ Ur,
                             const float* __restrict__ Wz, const float* __restrict__ Uz,
                             const float* __restrict__ Wh, const float* __restrict__ Uh,
                             short* __restrict__ BtP, short* __restrict__ BtE,
                             short* __restrict__ BtW2, short* __restrict__ BtRZ,
                             short* __restrict__ BtHW)
{
  int id = blockIdx.x * 256 + threadIdx.x;
  if (id < 262144){                       // BtP
    int jj = id >> 8, k = id & 255;
    float v = (jj < 512) ? W1[(size_t)k * 512 + jj] : W1[(size_t)(256 + k) * 512 + (jj - 512)];
    BtP[id] = f2bf(v);
  } else if (id < 294912){                // BtE pre-swizzled
    int i2 = id - 262144; int jj = i2 >> 6, c = i2 & 63;
    BtE[jj * 64 + (c ^ ((jj & 7) << 3))] = f2bf(W1[(size_t)(512 + c) * 512 + jj]);
  } else if (id < 425984){                // BtW2
    int i2 = id - 294912; int n = i2 >> 9, k = i2 & 511;
    BtW2[i2] = f2bf(W2[(size_t)k * 256 + n]);
  } else if (id < 688128){                // BtRZ
    int i2 = id - 425984; int col = i2 >> 9, k = i2 & 511;
    float v;
    if (col < 256) v = (k < 256) ? Wr[(size_t)k * 256 + col] : Ur[(size_t)(k - 256) * 256 + col];
    else { int c2 = col - 256; v = (k < 256) ? Wz[(size_t)k * 256 + c2] : Uz[(size_t)(k - 256) * 256 + c2]; }
    BtRZ[i2] = f2bf(v);
  } else if (id < 819200){                // BtHW
    int i2 = id - 688128; int col = i2 >> 9, k = i2 & 511;
    float v = (k < 256) ? Wh[(size_t)k * 256 + col] : Uh[(size_t)(k - 256) * 256 + col];
    BtHW[i2] = f2bf(v);
  }
}

// -------------------------------- readout ----------------------------------
__global__ __launch_bounds__(256)
void readout2(const float* __restrict__ g, const float* __restrict__ Wo,
              const float* __restrict__ bo, float* __restrict__ out){
  int t = threadIdx.x;
  int b = t >> 7, o = t & 127;
  float s = bo[o];
  for (int c = 0; c < 256; ++c) s += g[b * 256 + c] * Wo[c * 128 + o];
  out[b * 128 + o] = s;
}

// ===========================================================================
extern "C" void kernel_launch(void* const* d_in, const int* in_sizes, int n_in,
                              void* d_out, int out_size, void* d_ws, size_t ws_size,
                              hipStream_t stream)
{
  const float* ef  = (const float*)d_in[0];
  const float* W1  = (const float*)d_in[1];
  const float* b1  = (const float*)d_in[2];
  const float* W2  = (const float*)d_in[3];
  const float* b2  = (const float*)d_in[4];
  const float* Wr  = (const float*)d_in[5];
  const float* Ur  = (const float*)d_in[6];
  const float* br  = (const float*)d_in[7];
  const float* Wz  = (const float*)d_in[8];
  const float* Uz  = (const float*)d_in[9];
  const float* bz  = (const float*)d_in[10];
  const float* Wh  = (const float*)d_in[11];
  const float* Uh  = (const float*)d_in[12];
  const float* bh  = (const float*)d_in[13];
  const float* Wo  = (const float*)d_in[14];
  const float* bo  = (const float*)d_in[15];
  const int* esrc  = (const int*)d_in[16];
  const int* edst  = (const int*)d_in[17];

  char* base = (char*)d_ws;
  size_t off = 0;
  auto alloc = [&](size_t bytes) -> char* {
    off = (off + 255) & ~(size_t)255;
    char* p = base + off;
    off += bytes;
    return p;
  };
  float* h    = (float*)alloc((size_t)NB * 256 * 4);            // 16 MB
  float* m    = (float*)alloc((size_t)NB * 256 * 4);            // 16 MB
  short* P    = (short*)alloc((size_t)NB * 1024 * 2);           // 32 MB
  short* S    = (short*)alloc((size_t)NB * 512 * 2);            // 16 MB
  unsigned char* E1 = (unsigned char*)alloc((size_t)E_EDGES * 2 * MLPH); // 128 MiB
  short* BtP  = (short*)alloc(262144 * 2);
  short* BtE  = (short*)alloc(32768 * 2);
  short* BtW2 = (short*)alloc(131072 * 2);
  short* BtRZ = (short*)alloc(262144 * 2);
  short* BtHW = (short*)alloc(131072 * 2);
  int* counts = (int*)alloc(NNODES * 4);
  int* rs     = (int*)alloc((NNODES + 1) * 4);
  int* cursor = (int*)alloc(NNODES * 4);
  int* ceid   = (int*)alloc(E_EDGES * 4);
  int* csrc   = (int*)alloc(E_EDGES * 4);
  float* g    = (float*)alloc(512 * 4);
  // total ~216 MB < 256 MiB workspace

  dim3 blk(256);

  // ------------------------------- prep ----------------------------------
  hipMemsetAsync(g,  0, 512 * 4, stream);
  hipMemsetAsync(counts, 0, NNODES * 4, stream);
  prep_weights<<<3200, blk, 0, stream>>>(W1, W2, Wr, Ur, Wz, Uz, Wh, Uh,
                                         BtP, BtE, BtW2, BtRZ, BtHW);
  count_kernel<<<512, blk, 0, stream>>>(edst, counts);
  scan_kernel<<<1, 1024, 0, stream>>>(counts, rs, cursor);
  fill_kernel<<<512, blk, 0, stream>>>(edst, esrc, cursor, ceid, csrc);

  // E1 (fp8) computed ONCE — iteration-invariant
  e1_gemm<<<E_EDGES * 2 / 128, blk, 0, stream>>>(ef, BtE, E1, b1, ceid);

  // ----------------------------- iterations ------------------------------
  edge_kernel<false><<<NNODES, blk, 0, stream>>>(P, E1, csrc, rs, S);
  node_update<0><<<NB / RB, dim3(512), 0, stream>>>(S, P, m, h, g,
      BtW2, BtRZ, BtHW, BtP, counts, b2, br, bz, bh);

  edge_kernel<true><<<NNODES, blk, 0, stream>>>(P, E1, csrc, rs, S);
  node_update<1><<<NB / RB, dim3(512), 0, stream>>>(S, P, m, h, g,
      BtW2, BtRZ, BtHW, BtP, counts, b2, br, bz, bh);

  edge_kernel<true><<<NNODES, blk, 0, stream>>>(P, E1, csrc, rs, S);
  node_update<2><<<NB / RB, dim3(512), 0, stream>>>(S, P, m, h, g,
      BtW2, BtRZ, BtHW, BtP, counts, b2, br, bz, bh);

  // ------------------------------ readout --------------------------------
  readout2<<<1, blk, 0, stream>>>(g, Wo, bo, (float*)d_out);
}

// Round 16
// 420.077 us; speedup vs baseline: 1.0446x; 1.0446x over previous
//
#include <hip/hip_runtime.h>
#include <hip/hip_bf16.h>

#define E_EDGES 131072
#define NNODES  8192
#define NB      16384   // N_NODES * BATCH rows
#define HID     256
#define EDIM    64
#define MLPH    512
#define OUTD    128
#define NIT     3
#define RB      32      // rows per node_update block

typedef short s16x4 __attribute__((ext_vector_type(4)));
typedef short s16x8 __attribute__((ext_vector_type(8)));
typedef float f32x4 __attribute__((ext_vector_type(4)));
typedef float f32x2 __attribute__((ext_vector_type(2)));
typedef unsigned int u32x4 __attribute__((ext_vector_type(4)));

__device__ __forceinline__ short f2bf(float f){
  unsigned int x = __builtin_bit_cast(unsigned int, f);
  x += 0x7fffu + ((x >> 16) & 1u);          // RNE
  return (short)(x >> 16);
}
__device__ __forceinline__ float bf2f(short s){
  unsigned int x = ((unsigned int)(unsigned short)s) << 16;
  return __builtin_bit_cast(float, x);
}
__device__ __forceinline__ void gload_lds16(const void* g, void* l){
  __builtin_amdgcn_global_load_lds(
      (const __attribute__((address_space(1))) void*)g,
      (__attribute__((address_space(3))) void*)l, 16, 0, 0);
}
#define MFMA16(a,b,c) __builtin_amdgcn_mfma_f32_16x16x32_bf16((a),(b),(c),0,0,0)

// ---------------- fp8 (e4m3-style) encode/decode ----------------
#if defined(__has_builtin)
#if __has_builtin(__builtin_amdgcn_cvt_pk_f32_fp8) && __has_builtin(__builtin_amdgcn_cvt_pk_fp8_f32)
#define FP8_HW 1
#endif
#endif
#ifndef FP8_HW
#define FP8_HW 0
#endif

__device__ __forceinline__ unsigned char enc_fp8_sw(float f){
  unsigned int b = __builtin_bit_cast(unsigned int, f);
  unsigned int s = (b >> 24) & 0x80u;
  float a = fabsf(f);
  if (a >= 448.f) return (unsigned char)(s | 0x7e);       // clamp to 448
  if (a < 0.015625f){                                      // denorm: m*2^-9
    int q = (int)rintf(a * 512.f);                         // 0..8
    return (unsigned char)(s | (unsigned int)q);           // q==8 -> e=1,m=0
  }
  unsigned int e32  = (b >> 23) & 0xff;
  unsigned int mant = b & 0x7fffff;
  unsigned int rnd  = mant + 0x7ffff + ((mant >> 20) & 1); // RNE at bit 20
  unsigned int e8   = e32 - 120 + (rnd >> 23);
  unsigned int m3   = (rnd >> 20) & 7;
  if (e8 >= 16) return (unsigned char)(s | 0x7e);
  return (unsigned char)(s | (e8 << 3) | m3);
}
__device__ __forceinline__ float dec_fp8_sw(unsigned int v){
  unsigned int s = (v >> 7) & 1, e = (v >> 3) & 15, m = v & 7;
  float r;
  if (e == 0) r = (float)m * 0.001953125f;                 // m * 2^-9
  else        r = __builtin_bit_cast(float, ((e + 120u) << 23) | (m << 20));
  return s ? -r : r;
}
__device__ __forceinline__ unsigned char enc_fp8(float f){
#if FP8_HW
  unsigned int pk = (unsigned int)__builtin_amdgcn_cvt_pk_fp8_f32(f, f, 0, false);
  return (unsigned char)(pk & 0xff);
#else
  return enc_fp8_sw(f);
#endif
}
__device__ __forceinline__ void dec_fp8x4(unsigned int ev, float& e0, float& e1,
                                          float& e2, float& e3){
#if FP8_HW
  f32x2 lo = __builtin_amdgcn_cvt_pk_f32_fp8((int)ev, false);
  f32x2 hi = __builtin_amdgcn_cvt_pk_f32_fp8((int)ev, true);
  e0 = lo[0]; e1 = lo[1]; e2 = hi[0]; e3 = hi[1];
#else
  e0 = dec_fp8_sw(ev & 0xff); e1 = dec_fp8_sw((ev >> 8) & 0xff);
  e2 = dec_fp8_sw((ev >> 16) & 0xff); e3 = dec_fp8_sw(ev >> 24);
#endif
}

// ===========================================================================
// e1_gemm v3 — runs ONCE. Block = 128 CSR rows; loops ALL 4 column panels
// in-block (A staged once -> ef fetched once). Swapped-operand MFMA packs
// 4 fp8/lane -> u32 into LDS tile Ts (swizzled, conflict-free), then
// coalesced 16B stores (lane-pairs = contiguous 32B sectors).
// ===========================================================================
__global__ __launch_bounds__(256, 3)
void e1_gemm(const float* __restrict__ ef, const short* __restrict__ BtE,
             unsigned char* __restrict__ E1, const float* __restrict__ b1,
             const int* __restrict__ ceid)
{
  __shared__ __align__(16) short As[128 * 64];          // 16 KB swizzled
  __shared__ __align__(16) short Bs[128 * 64];          // 16 KB swizzled
  __shared__ __align__(16) unsigned char Ts[128 * 128]; // 16 KB out panel

  const int t  = threadIdx.x;
  const int w  = t >> 6, l = t & 63;
  const int lr = l & 15, lg = l >> 4;
  const int wr = w >> 1, wc = w & 1;
  const int browbase = blockIdx.x * 128;
  const int srow = t >> 3;
  const int scol = (t & 7) * 8;

  // ---- stage A once: gather f32 -> bf16 -> swizzled ds_write ----
#pragma unroll
  for (int i = 0; i < 4; ++i){
    int R = browbase + srow + i * 32;
    int e = ceid[R >> 1];
    const float* ap = ef + ((size_t)e * 2 + (R & 1)) * EDIM + scol;
    f32x4 f0 = *(const f32x4*)ap;
    f32x4 f1 = *(const f32x4*)(ap + 4);
    s16x8 o;
    o[0]=f2bf(f0[0]); o[1]=f2bf(f0[1]); o[2]=f2bf(f0[2]); o[3]=f2bf(f0[3]);
    o[4]=f2bf(f1[0]); o[5]=f2bf(f1[1]); o[6]=f2bf(f1[2]); o[7]=f2bf(f1[3]);
    int row = srow + i * 32;
    *(s16x8*)(As + row * 64 + (scol ^ ((row & 7) << 3))) = o;
  }

  for (int pn = 0; pn < 4; ++pn){
    // ---- stage B panel (pre-swizzled global rows pn*128..+127) ----
#pragma unroll
    for (int i = 0; i < 4; ++i)
      gload_lds16(BtE + (size_t)(pn * 128 + srow + i * 32) * 64 + scol,
                  (char*)Bs + w * 1024 + i * 4096);
    __syncthreads();          // As+Bs staged; prev panel's Ts reads done

    f32x4 acc[4][4];          // [mf = mlph frag][e2 = edge frag]
#pragma unroll
    for (int mf = 0; mf < 4; ++mf)
#pragma unroll
      for (int e2 = 0; e2 < 4; ++e2) acc[mf][e2] = (f32x4){0.f,0.f,0.f,0.f};

#pragma unroll
    for (int kk = 0; kk < 2; ++kk){
      s16x8 a[4], b[4];
#pragma unroll
      for (int e2 = 0; e2 < 4; ++e2){
        int ar = wr*64 + e2*16 + lr;
        a[e2] = *(const s16x8*)(As + ar * 64 + ((kk*32 + lg*8) ^ ((ar & 7) << 3)));
      }
#pragma unroll
      for (int mf = 0; mf < 4; ++mf){
        int br = wc*64 + mf*16 + lr;
        b[mf] = *(const s16x8*)(Bs + br * 64 + ((kk*32 + lg*8) ^ ((br & 7) << 3)));
      }
#pragma unroll
      for (int mf = 0; mf < 4; ++mf)
#pragma unroll
        for (int e2 = 0; e2 < 4; ++e2)
          acc[mf][e2] = MFMA16(b[mf], a[e2], acc[mf][e2]);   // swapped
    }

    // ---- epilogue: pack 4 fp8 -> u32 -> Ts (16B-unit swizzle ^ row&7) ----
#pragma unroll
    for (int mf = 0; mf < 4; ++mf){
      int mloc = wc*64 + mf*16 + lg*4;                 // panel-local col
      f32x4 bv = *(const f32x4*)(b1 + pn*128 + mloc);
      int u = mloc >> 2;                               // u32 unit 0..31
      int usw_hi = (u >> 2), ulo = (u & 3) << 2;
#pragma unroll
      for (int e2 = 0; e2 < 4; ++e2){
        int erow = wr*64 + e2*16 + lr;
        unsigned int pk = (unsigned int)enc_fp8(acc[mf][e2][0] + bv[0])
                        | ((unsigned int)enc_fp8(acc[mf][e2][1] + bv[1]) << 8)
                        | ((unsigned int)enc_fp8(acc[mf][e2][2] + bv[2]) << 16)
                        | ((unsigned int)enc_fp8(acc[mf][e2][3] + bv[3]) << 24);
        *(unsigned int*)(Ts + erow * 128 + ((usw_hi ^ (erow & 7)) << 4) + ulo) = pk;
      }
    }
    __syncthreads();          // Ts visible

    // ---- coalesced store: 2 threads/row, lane-pair = contiguous 32B ----
    {
      int rr = t >> 1, hh = t & 1;
#pragma unroll
      for (int q = 0; q < 4; ++q){
        int u16 = q * 2 + hh;                          // 16B unit 0..7
        u32x4 v = *(const u32x4*)(Ts + rr * 128 + ((u16 ^ (rr & 7)) << 4));
        *(u32x4*)(E1 + (size_t)(browbase + rr) * 512 + pn * 128 + u16 * 16) = v;
      }
    }
  }
}

// ===========================================================================
// edge_kernel: S[n] = sum_{e: dst=n} relu(P1[n] + P2[src] + E1[e])  (E1 fp8)
// ===========================================================================
template<bool USE_P>
__global__ __launch_bounds__(256)
void edge_kernel(const short* __restrict__ P, const unsigned char* __restrict__ E1,
                 const int* __restrict__ csr_src, const int* __restrict__ row_start,
                 short* __restrict__ S)
{
  const int n = blockIdx.x;
  const int t = threadIdx.x;
  const int b = t >> 7;
  const int j = (t & 127) << 2;
  const int ps = row_start[n], pe = row_start[n + 1];

  float p10 = 0.f, p11 = 0.f, p12 = 0.f, p13 = 0.f;
  if (USE_P){
    s16x4 t1 = *(const s16x4*)(P + (size_t)(n * 2 + b) * 1024 + j);
    p10 = bf2f(t1[0]); p11 = bf2f(t1[1]); p12 = bf2f(t1[2]); p13 = bf2f(t1[3]);
  }
  float a0 = 0.f, a1 = 0.f, a2 = 0.f, a3 = 0.f;
  for (int p = ps; p < pe; ++p){
    unsigned int ev = *(const unsigned int*)(E1 + ((size_t)p * 2 + b) * 512 + j);
    float e0, e1, e2, e3;
    dec_fp8x4(ev, e0, e1, e2, e3);
    float x0 = p10 + e0, x1 = p11 + e1, x2 = p12 + e2, x3 = p13 + e3;
    if (USE_P){
      int src = csr_src[p];
      s16x4 v2 = *(const s16x4*)(P + (size_t)(src * 2 + b) * 1024 + 512 + j);
      x0 += bf2f(v2[0]); x1 += bf2f(v2[1]); x2 += bf2f(v2[2]); x3 += bf2f(v2[3]);
    }
    a0 += fmaxf(x0, 0.f); a1 += fmaxf(x1, 0.f);
    a2 += fmaxf(x2, 0.f); a3 += fmaxf(x3, 0.f);
  }
  s16x4 o; o[0] = f2bf(a0); o[1] = f2bf(a1); o[2] = f2bf(a2); o[3] = f2bf(a3);
  *(s16x4*)(S + (size_t)(n * 2 + b) * 512 + j) = o;
}

// ===========================================================================
// node_update — staged-B template, 512 threads (8 waves = 2 row-halves x
// 4 col-quarters), RB=32, LDS 68KB -> 2 blocks/CU = 16 waves/CU.
// PH0: K=256 gates; PH2: readout.  (R12 replay-proven version.)
// ===========================================================================
template<int PH>
__global__ __launch_bounds__(512, 4)
void node_update(const short* __restrict__ S, short* __restrict__ Pout,
                 float* __restrict__ m, float* __restrict__ h,
                 float* __restrict__ g,
                 const short* __restrict__ BtW2, const short* __restrict__ BtRZ,
                 const short* __restrict__ BtHW, const short* __restrict__ BtP,
                 const int* __restrict__ deg, const float* __restrict__ b2,
                 const float* __restrict__ br, const float* __restrict__ bz,
                 const float* __restrict__ bh)
{
  __shared__ __align__(16) char lds[69632];
  short* As = (short*)lds;             // [32][64]   4KB
  short* Bs = (short*)(lds + 4096);    // [256][64] 32KB
  short* Ms = (short*)(lds + 36864);   // [32][256] 16KB
  short* Xs = (short*)(lds + 53248);   // [32][256] 16KB
  float* Hf = (float*)lds;             // [32][256] 32KB overlay (PH2 only)

  const int tid = threadIdx.x;
  const int w = tid >> 6, l = tid & 63;
  const int lr = l & 15, lg = l >> 4;
  const int wq = w >> 2, wc = w & 3;   // row-half, col-quarter
  const int grow0 = blockIdx.x * RB;

  auto stageB = [&](const short* Bt, int K, int pcol0, int k0){
#pragma unroll
    for (int i = 0; i < 4; ++i){
      int u = i * 512 + tid;
      int row = u >> 3, uc = u & 7;
      const short* gp = Bt + (size_t)(pcol0 + row) * K + k0 + ((uc ^ (row & 7)) << 3);
      gload_lds16(gp, (char*)Bs + i * 8192 + w * 1024);
    }
  };
  auto stageA_S = [&](int k0){
    if (w < 4){
      int u = w * 64 + l;
      int row = u >> 3, uc = u & 7;
      const short* gp = S + (size_t)(grow0 + row) * 512 + k0 + ((uc ^ (row & 7)) << 3);
      gload_lds16(gp, (char*)As + w * 1024);
    }
  };
  auto rdA64 = [&](int row, int colel){ return row * 64 + (colel ^ ((row & 7) << 3)); };
  auto rd256 = [&](int row, int colel){ return row * 256 + (colel ^ ((row & 7) << 3)); };

  // ---- h into regs, acc init = m + deg*b2; Xs <- bf16(h) ----
  f32x4 hv[4], acc[4];
#pragma unroll
  for (int j = 0; j < 4; ++j)
#pragma unroll
    for (int r = 0; r < 4; ++r){
      int rl = wq*16 + lg*4 + r, colp = wc*64 + j*16 + lr;
      size_t gi = (size_t)(grow0 + rl) * 256 + colp;
      float base = (float)deg[(grow0 + rl) >> 1] * b2[colp];
      if (PH > 0){ base += m[gi]; hv[j][r] = h[gi]; }
      else hv[j][r] = 0.f;
      acc[j][r] = base;
    }
  if (PH > 0){
#pragma unroll
    for (int j = 0; j < 4; ++j)
#pragma unroll
      for (int r = 0; r < 4; ++r){
        int rl = wq*16 + lg*4 + r, colp = wc*64 + j*16 + lr;
        Xs[rd256(rl, colp)] = f2bf(hv[j][r]);
      }
  }

  // ---- Phase A: acc += S @ W2 (K=512, 8 staged chunks) ----
  for (int c = 0; c < 8; ++c){
    __syncthreads();
    stageA_S(c * 64);
    stageB(BtW2, 512, 0, c * 64);
    __syncthreads();
#pragma unroll
    for (int kk = 0; kk < 2; ++kk){
      s16x8 a0 = *(const s16x8*)(As + rdA64(wq*16 + lr, kk*32 + lg*8));
#pragma unroll
      for (int j = 0; j < 4; ++j){
        s16x8 bb = *(const s16x8*)(Bs + rdA64(wc*64 + j*16 + lr, kk*32 + lg*8));
        acc[j] = MFMA16(a0, bb, acc[j]);
      }
    }
  }
#pragma unroll
  for (int j = 0; j < 4; ++j)
#pragma unroll
    for (int r = 0; r < 4; ++r){
      int rl = wq*16 + lg*4 + r, colp = wc*64 + j*16 + lr;
      float v = acc[j][r];
      if (PH < 2) m[(size_t)(grow0 + rl) * 256 + colp] = v;
      Ms[rd256(rl, colp)] = f2bf(v);
    }

  const int NC = (PH > 0) ? 8 : 4;       // gate K-chunks (PH0: U-half is zero)

  // ---- Phase B: Gr ----
  f32x4 Gr[4], Gz[4];
#pragma unroll
  for (int j = 0; j < 4; ++j){ Gr[j] = (f32x4){0.f,0.f,0.f,0.f}; Gz[j] = (f32x4){0.f,0.f,0.f,0.f}; }

  for (int c = 0; c < NC; ++c){
    __syncthreads();
    stageB(BtRZ, 512, 0, c * 64);
    __syncthreads();
    const short* Ab = (c < 4) ? Ms : Xs;
    int kb = (c & 3) * 64;
#pragma unroll
    for (int kk = 0; kk < 2; ++kk){
      s16x8 a0 = *(const s16x8*)(Ab + rd256(wq*16 + lr, kb + kk*32 + lg*8));
#pragma unroll
      for (int j = 0; j < 4; ++j){
        s16x8 bb = *(const s16x8*)(Bs + rdA64(wc*64 + j*16 + lr, kk*32 + lg*8));
        Gr[j] = MFMA16(a0, bb, Gr[j]);
      }
    }
  }
  // ---- Phase C: Gz ----
  for (int c = 0; c < NC; ++c){
    __syncthreads();
    stageB(BtRZ, 512, 256, c * 64);
    __syncthreads();
    const short* Ab = (c < 4) ? Ms : Xs;
    int kb = (c & 3) * 64;
#pragma unroll
    for (int kk = 0; kk < 2; ++kk){
      s16x8 a0 = *(const s16x8*)(Ab + rd256(wq*16 + lr, kb + kk*32 + lg*8));
#pragma unroll
      for (int j = 0; j < 4; ++j){
        s16x8 bb = *(const s16x8*)(Bs + rdA64(wc*64 + j*16 + lr, kk*32 + lg*8));
        Gz[j] = MFMA16(a0, bb, Gz[j]);
      }
    }
  }

  // ---- e1: r, z; Xs <- bf16(r*h) ----
  f32x4 zz[4];
#pragma unroll
  for (int j = 0; j < 4; ++j)
#pragma unroll
    for (int r = 0; r < 4; ++r){
      int colp = wc*64 + j*16 + lr;
      zz[j][r] = 1.f / (1.f + __expf(-(Gz[j][r] + bz[colp])));
    }
  if (PH > 0){
    __syncthreads();                     // B/C's Xs(hb) reads done
#pragma unroll
    for (int j = 0; j < 4; ++j)
#pragma unroll
      for (int r = 0; r < 4; ++r){
        int rl = wq*16 + lg*4 + r, colp = wc*64 + j*16 + lr;
        float rr = 1.f / (1.f + __expf(-(Gr[j][r] + br[colp])));
        Xs[rd256(rl, colp)] = f2bf(rr * hv[j][r]);
      }
    __syncthreads();                     // Xs(rh) visible
  }

  // ---- Phase D: Gw = [m|rh] @ BtHW ----
  f32x4 Gw[4];
#pragma unroll
  for (int j = 0; j < 4; ++j) Gw[j] = (f32x4){0.f,0.f,0.f,0.f};
  for (int c = 0; c < NC; ++c){
    __syncthreads();
    stageB(BtHW, 512, 0, c * 64);
    __syncthreads();
    const short* Ab = (c < 4) ? Ms : Xs;
    int kb = (c & 3) * 64;
#pragma unroll
    for (int kk = 0; kk < 2; ++kk){
      s16x8 a0 = *(const s16x8*)(Ab + rd256(wq*16 + lr, kb + kk*32 + lg*8));
#pragma unroll
      for (int j = 0; j < 4; ++j){
        s16x8 bb = *(const s16x8*)(Bs + rdA64(wc*64 + j*16 + lr, kk*32 + lg*8));
        Gw[j] = MFMA16(a0, bb, Gw[j]);
      }
    }
  }

  // ---- e2: h' ----
  __syncthreads();                       // D's Ms/Xs reads done
#pragma unroll
  for (int j = 0; j < 4; ++j)
#pragma unroll
    for (int r = 0; r < 4; ++r){
      int rl = wq*16 + lg*4 + r, colp = wc*64 + j*16 + lr;
      float ht = tanhf(Gw[j][r] + bh[colp]);
      float z  = zz[j][r];
      float hn = (1.f - z) * hv[j][r] + z * ht;
      if (PH < 2){
        h[(size_t)(grow0 + rl) * 256 + colp] = hn;
        Ms[rd256(rl, colp)] = f2bf(hn);
      } else {
        Hf[rl * 256 + colp] = hn;
      }
    }
  __syncthreads();                       // Ms(h') / Hf visible

  if (PH < 2){
    // ---- Phase E: P = h' @ BtP, 4 panels of 256 cols ----
    for (int pn = 0; pn < 4; ++pn){
      f32x4 pa[4];
#pragma unroll
      for (int j = 0; j < 4; ++j) pa[j] = (f32x4){0.f,0.f,0.f,0.f};
      for (int c = 0; c < 4; ++c){
        __syncthreads();
        stageB(BtP, 256, pn * 256, c * 64);
        __syncthreads();
#pragma unroll
        for (int kk = 0; kk < 2; ++kk){
          s16x8 a0 = *(const s16x8*)(Ms + rd256(wq*16 + lr, c*64 + kk*32 + lg*8));
#pragma unroll
          for (int j = 0; j < 4; ++j){
            s16x8 bb = *(const s16x8*)(Bs + rdA64(wc*64 + j*16 + lr, kk*32 + lg*8));
            pa[j] = MFMA16(a0, bb, pa[j]);
          }
        }
      }
#pragma unroll
      for (int j = 0; j < 4; ++j)
#pragma unroll
        for (int r = 0; r < 4; ++r){
          int colp = wc*64 + j*16 + lr;
          Pout[(size_t)(grow0 + wq*16 + lg*4 + r) * 1024 + pn*256 + colp] = f2bf(pa[j][r]);
        }
    }
  } else {
    // ---- readout partial: g[b*256+c] += sum rows ----
    int col = tid & 255, pb = (tid >> 8) & 1;
    float s = 0.f;
#pragma unroll
    for (int rr = 0; rr < 16; ++rr)
      s += Hf[(2*rr + pb) * 256 + col];
    atomicAdd(&g[pb * 256 + col], s);
  }
}

// ------------------------------- CSR build ---------------------------------
__global__ void count_kernel(const int* __restrict__ edst, int* __restrict__ counts){
  int e = blockIdx.x * 256 + threadIdx.x;
  if (e < E_EDGES) atomicAdd(&counts[edst[e]], 1);
}
__global__ void scan_kernel(const int* __restrict__ counts, int* __restrict__ row_start,
                            int* __restrict__ cursor){
  __shared__ int sums[1024];
  int t = threadIdx.x;
  int base = t * 8;
  int loc[8]; int s = 0;
#pragma unroll
  for (int i = 0; i < 8; ++i){ loc[i] = s; s += counts[base + i]; }
  sums[t] = s;
  __syncthreads();
  for (int o = 1; o < 1024; o <<= 1){
    int v = sums[t];
    int u = (t >= o) ? sums[t - o] : 0;
    __syncthreads();
    sums[t] = v + u;
    __syncthreads();
  }
  int excl = (t == 0) ? 0 : sums[t - 1];
#pragma unroll
  for (int i = 0; i < 8; ++i){ int v = excl + loc[i]; row_start[base + i] = v; cursor[base + i] = v; }
  if (t == 1023) row_start[NNODES] = sums[1023];
}
__global__ void fill_kernel(const int* __restrict__ edst, const int* __restrict__ esrc,
                            int* __restrict__ cursor, int* __restrict__ csr_eid,
                            int* __restrict__ csr_src){
  int e = blockIdx.x * 256 + threadIdx.x;
  if (e < E_EDGES){
    int pos = atomicAdd(&cursor[edst[e]], 1);
    csr_eid[pos] = e;
    csr_src[pos] = esrc[e];
  }
}

// --------------------------- weight repacking ------------------------------
// BtP [1024][256], BtE [512][64] PRE-SWIZZLED, BtW2 [256][512],
// BtRZ [512][512] (cols r|z, K = W|U), BtHW [256][512] (K = Wh|Uh)
__global__ void prep_weights(const float* __restrict__ W1, const float* __restrict__ W2,
                             const float* __restrict__ Wr, const float* __restrict__ Ur,
                             const float* __restrict__ Wz, const float* __restrict__ Uz,
                             const float* __restrict__ Wh, const float* __restrict__ Uh,
                             short* __restrict__ BtP, short* __restrict__ BtE,
                             short* __restrict__ BtW2, short* __restrict__ BtRZ,
                             short* __restrict__ BtHW)
{
  int id = blockIdx.x * 256 + threadIdx.x;
  if (id < 262144){                       // BtP
    int jj = id >> 8, k = id & 255;
    float v = (jj < 512) ? W1[(size_t)k * 512 + jj] : W1[(size_t)(256 + k) * 512 + (jj - 512)];
    BtP[id] = f2bf(v);
  } else if (id < 294912){                // BtE pre-swizzled
    int i2 = id - 262144; int jj = i2 >> 6, c = i2 & 63;
    BtE[jj * 64 + (c ^ ((jj & 7) << 3))] = f2bf(W1[(size_t)(512 + c) * 512 + jj]);
  } else if (id < 425984){                // BtW2
    int i2 = id - 294912; int n = i2 >> 9, k = i2 & 511;
    BtW2[i2] = f2bf(W2[(size_t)k * 256 + n]);
  } else if (id < 688128){                // BtRZ
    int i2 = id - 425984; int col = i2 >> 9, k = i2 & 511;
    float v;
    if (col < 256) v = (k < 256) ? Wr[(size_t)k * 256 + col] : Ur[(size_t)(k - 256) * 256 + col];
    else { int c2 = col - 256; v = (k < 256) ? Wz[(size_t)k * 256 + c2] : Uz[(size_t)(k - 256) * 256 + c2]; }
    BtRZ[i2] = f2bf(v);
  } else if (id < 819200){                // BtHW
    int i2 = id - 688128; int col = i2 >> 9, k = i2 & 511;
    float v = (k < 256) ? Wh[(size_t)k * 256 + col] : Uh[(size_t)(k - 256) * 256 + col];
    BtHW[i2] = f2bf(v);
  }
}

// -------------------------------- readout ----------------------------------
__global__ __launch_bounds__(256)
void readout2(const float* __restrict__ g, const float* __restrict__ Wo,
              const float* __restrict__ bo, float* __restrict__ out){
  int t = threadIdx.x;
  int b = t >> 7, o = t & 127;
  float s = bo[o];
  for (int c = 0; c < 256; ++c) s += g[b * 256 + c] * Wo[c * 128 + o];
  out[b * 128 + o] = s;
}

// ===========================================================================
extern "C" void kernel_launch(void* const* d_in, const int* in_sizes, int n_in,
                              void* d_out, int out_size, void* d_ws, size_t ws_size,
                              hipStream_t stream)
{
  const float* ef  = (const float*)d_in[0];
  const float* W1  = (const float*)d_in[1];
  const float* b1  = (const float*)d_in[2];
  const float* W2  = (const float*)d_in[3];
  const float* b2  = (const float*)d_in[4];
  const float* Wr  = (const float*)d_in[5];
  const float* Ur  = (const float*)d_in[6];
  const float* br  = (const float*)d_in[7];
  const float* Wz  = (const float*)d_in[8];
  const float* Uz  = (const float*)d_in[9];
  const float* bz  = (const float*)d_in[10];
  const float* Wh  = (const float*)d_in[11];
  const float* Uh  = (const float*)d_in[12];
  const float* bh  = (const float*)d_in[13];
  const float* Wo  = (const float*)d_in[14];
  const float* bo  = (const float*)d_in[15];
  const int* esrc  = (const int*)d_in[16];
  const int* edst  = (const int*)d_in[17];

  char* base = (char*)d_ws;
  size_t off = 0;
  auto alloc = [&](size_t bytes) -> char* {
    off = (off + 255) & ~(size_t)255;
    char* p = base + off;
    off += bytes;
    return p;
  };
  float* h    = (float*)alloc((size_t)NB * 256 * 4);            // 16 MB
  float* m    = (float*)alloc((size_t)NB * 256 * 4);            // 16 MB
  short* P    = (short*)alloc((size_t)NB * 1024 * 2);           // 32 MB
  short* S    = (short*)alloc((size_t)NB * 512 * 2);            // 16 MB
  unsigned char* E1 = (unsigned char*)alloc((size_t)E_EDGES * 2 * MLPH); // 128 MiB
  short* BtP  = (short*)alloc(262144 * 2);
  short* BtE  = (short*)alloc(32768 * 2);
  short* BtW2 = (short*)alloc(131072 * 2);
  short* BtRZ = (short*)alloc(262144 * 2);
  short* BtHW = (short*)alloc(131072 * 2);
  int* counts = (int*)alloc(NNODES * 4);
  int* rs     = (int*)alloc((NNODES + 1) * 4);
  int* cursor = (int*)alloc(NNODES * 4);
  int* ceid   = (int*)alloc(E_EDGES * 4);
  int* csrc   = (int*)alloc(E_EDGES * 4);
  float* g    = (float*)alloc(512 * 4);
  // total ~216 MB < 256 MiB workspace

  dim3 blk(256);

  // ------------------------------- prep ----------------------------------
  hipMemsetAsync(g,  0, 512 * 4, stream);
  hipMemsetAsync(counts, 0, NNODES * 4, stream);
  prep_weights<<<3200, blk, 0, stream>>>(W1, W2, Wr, Ur, Wz, Uz, Wh, Uh,
                                         BtP, BtE, BtW2, BtRZ, BtHW);
  count_kernel<<<512, blk, 0, stream>>>(edst, counts);
  scan_kernel<<<1, 1024, 0, stream>>>(counts, rs, cursor);
  fill_kernel<<<512, blk, 0, stream>>>(edst, esrc, cursor, ceid, csrc);

  // E1 (fp8) computed ONCE — iteration-invariant
  e1_gemm<<<E_EDGES * 2 / 128, blk, 0, stream>>>(ef, BtE, E1, b1, ceid);

  // ----------------------------- iterations ------------------------------
  edge_kernel<false><<<NNODES, blk, 0, stream>>>(P, E1, csrc, rs, S);
  node_update<0><<<NB / RB, dim3(512), 0, stream>>>(S, P, m, h, g,
      BtW2, BtRZ, BtHW, BtP, counts, b2, br, bz, bh);

  edge_kernel<true><<<NNODES, blk, 0, stream>>>(P, E1, csrc, rs, S);
  node_update<1><<<NB / RB, dim3(512), 0, stream>>>(S, P, m, h, g,
      BtW2, BtRZ, BtHW, BtP, counts, b2, br, bz, bh);

  edge_kernel<true><<<NNODES, blk, 0, stream>>>(P, E1, csrc, rs, S);
  node_update<2><<<NB / RB, dim3(512), 0, stream>>>(S, P, m, h, g,
      BtW2, BtRZ, BtHW, BtP, counts, b2, br, bz, bh);

  // ------------------------------ readout --------------------------------
  readout2<<<1, blk, 0, stream>>>(g, Wo, bo, (float*)d_out);
}

// Round 17
// 408.826 us; speedup vs baseline: 1.0733x; 1.0275x over previous
//
#include <hip/hip_runtime.h>
#include <hip/hip_bf16.h>

#define E_EDGES 131072
#define NNODES  8192
#define NB      16384   // N_NODES * BATCH rows
#define HID     256
#define EDIM    64
#define MLPH    512
#define OUTD    128
#define NIT     3
#define RB      32      // rows per node_update block

typedef short s16x4 __attribute__((ext_vector_type(4)));
typedef short s16x8 __attribute__((ext_vector_type(8)));
typedef float f32x4 __attribute__((ext_vector_type(4)));
typedef float f32x2 __attribute__((ext_vector_type(2)));
typedef unsigned int u32x2 __attribute__((ext_vector_type(2)));
typedef unsigned int u32x4 __attribute__((ext_vector_type(4)));

__device__ __forceinline__ short f2bf(float f){
  unsigned int x = __builtin_bit_cast(unsigned int, f);
  x += 0x7fffu + ((x >> 16) & 1u);          // RNE
  return (short)(x >> 16);
}
__device__ __forceinline__ float bf2f(short s){
  unsigned int x = ((unsigned int)(unsigned short)s) << 16;
  return __builtin_bit_cast(float, x);
}
__device__ __forceinline__ void gload_lds16(const void* g, void* l){
  __builtin_amdgcn_global_load_lds(
      (const __attribute__((address_space(1))) void*)g,
      (__attribute__((address_space(3))) void*)l, 16, 0, 0);
}
#define MFMA16(a,b,c) __builtin_amdgcn_mfma_f32_16x16x32_bf16((a),(b),(c),0,0,0)

// ---------------- fp8 (e4m3-style) encode/decode ----------------
#if defined(__has_builtin)
#if __has_builtin(__builtin_amdgcn_cvt_pk_f32_fp8) && __has_builtin(__builtin_amdgcn_cvt_pk_fp8_f32)
#define FP8_HW 1
#endif
#endif
#ifndef FP8_HW
#define FP8_HW 0
#endif

__device__ __forceinline__ unsigned char enc_fp8_sw(float f){
  unsigned int b = __builtin_bit_cast(unsigned int, f);
  unsigned int s = (b >> 24) & 0x80u;
  float a = fabsf(f);
  if (a >= 448.f) return (unsigned char)(s | 0x7e);       // clamp to 448
  if (a < 0.015625f){                                      // denorm: m*2^-9
    int q = (int)rintf(a * 512.f);                         // 0..8
    return (unsigned char)(s | (unsigned int)q);           // q==8 -> e=1,m=0
  }
  unsigned int e32  = (b >> 23) & 0xff;
  unsigned int mant = b & 0x7fffff;
  unsigned int rnd  = mant + 0x7ffff + ((mant >> 20) & 1); // RNE at bit 20
  unsigned int e8   = e32 - 120 + (rnd >> 23);
  unsigned int m3   = (rnd >> 20) & 7;
  if (e8 >= 16) return (unsigned char)(s | 0x7e);
  return (unsigned char)(s | (e8 << 3) | m3);
}
__device__ __forceinline__ float dec_fp8_sw(unsigned int v){
  unsigned int s = (v >> 7) & 1, e = (v >> 3) & 15, m = v & 7;
  float r;
  if (e == 0) r = (float)m * 0.001953125f;                 // m * 2^-9
  else        r = __builtin_bit_cast(float, ((e + 120u) << 23) | (m << 20));
  return s ? -r : r;
}
__device__ __forceinline__ unsigned char enc_fp8(float f){
#if FP8_HW
  unsigned int pk = (unsigned int)__builtin_amdgcn_cvt_pk_fp8_f32(f, f, 0, false);
  return (unsigned char)(pk & 0xff);
#else
  return enc_fp8_sw(f);
#endif
}
__device__ __forceinline__ void dec_fp8x4(unsigned int ev, float& e0, float& e1,
                                          float& e2, float& e3){
#if FP8_HW
  f32x2 lo = __builtin_amdgcn_cvt_pk_f32_fp8((int)ev, false);
  f32x2 hi = __builtin_amdgcn_cvt_pk_f32_fp8((int)ev, true);
  e0 = lo[0]; e1 = lo[1]; e2 = hi[0]; e3 = hi[1];
#else
  e0 = dec_fp8_sw(ev & 0xff); e1 = dec_fp8_sw((ev >> 8) & 0xff);
  e2 = dec_fp8_sw((ev >> 16) & 0xff); e3 = dec_fp8_sw(ev >> 24);
#endif
}

// ===========================================================================
// e1_gemm v3 (verified R12) — runs ONCE.
// ===========================================================================
__global__ __launch_bounds__(256, 3)
void e1_gemm(const float* __restrict__ ef, const short* __restrict__ BtE,
             unsigned char* __restrict__ E1, const float* __restrict__ b1,
             const int* __restrict__ ceid)
{
  __shared__ __align__(16) short As[128 * 64];          // 16 KB swizzled
  __shared__ __align__(16) short Bs[128 * 64];          // 16 KB swizzled
  __shared__ __align__(16) unsigned char Ts[128 * 128]; // 16 KB out panel

  const int t  = threadIdx.x;
  const int w  = t >> 6, l = t & 63;
  const int lr = l & 15, lg = l >> 4;
  const int wr = w >> 1, wc = w & 1;
  const int browbase = blockIdx.x * 128;
  const int srow = t >> 3;
  const int scol = (t & 7) * 8;

#pragma unroll
  for (int i = 0; i < 4; ++i){
    int R = browbase + srow + i * 32;
    int e = ceid[R >> 1];
    const float* ap = ef + ((size_t)e * 2 + (R & 1)) * EDIM + scol;
    f32x4 f0 = *(const f32x4*)ap;
    f32x4 f1 = *(const f32x4*)(ap + 4);
    s16x8 o;
    o[0]=f2bf(f0[0]); o[1]=f2bf(f0[1]); o[2]=f2bf(f0[2]); o[3]=f2bf(f0[3]);
    o[4]=f2bf(f1[0]); o[5]=f2bf(f1[1]); o[6]=f2bf(f1[2]); o[7]=f2bf(f1[3]);
    int row = srow + i * 32;
    *(s16x8*)(As + row * 64 + (scol ^ ((row & 7) << 3))) = o;
  }

  for (int pn = 0; pn < 4; ++pn){
#pragma unroll
    for (int i = 0; i < 4; ++i)
      gload_lds16(BtE + (size_t)(pn * 128 + srow + i * 32) * 64 + scol,
                  (char*)Bs + w * 1024 + i * 4096);
    __syncthreads();          // As+Bs staged; prev panel's Ts reads done

    f32x4 acc[4][4];
#pragma unroll
    for (int mf = 0; mf < 4; ++mf)
#pragma unroll
      for (int e2 = 0; e2 < 4; ++e2) acc[mf][e2] = (f32x4){0.f,0.f,0.f,0.f};

#pragma unroll
    for (int kk = 0; kk < 2; ++kk){
      s16x8 a[4], b[4];
#pragma unroll
      for (int e2 = 0; e2 < 4; ++e2){
        int ar = wr*64 + e2*16 + lr;
        a[e2] = *(const s16x8*)(As + ar * 64 + ((kk*32 + lg*8) ^ ((ar & 7) << 3)));
      }
#pragma unroll
      for (int mf = 0; mf < 4; ++mf){
        int br = wc*64 + mf*16 + lr;
        b[mf] = *(const s16x8*)(Bs + br * 64 + ((kk*32 + lg*8) ^ ((br & 7) << 3)));
      }
#pragma unroll
      for (int mf = 0; mf < 4; ++mf)
#pragma unroll
        for (int e2 = 0; e2 < 4; ++e2)
          acc[mf][e2] = MFMA16(b[mf], a[e2], acc[mf][e2]);   // swapped
    }

#pragma unroll
    for (int mf = 0; mf < 4; ++mf){
      int mloc = wc*64 + mf*16 + lg*4;
      f32x4 bv = *(const f32x4*)(b1 + pn*128 + mloc);
      int u = mloc >> 2;
      int usw_hi = (u >> 2), ulo = (u & 3) << 2;
#pragma unroll
      for (int e2 = 0; e2 < 4; ++e2){
        int erow = wr*64 + e2*16 + lr;
        unsigned int pk = (unsigned int)enc_fp8(acc[mf][e2][0] + bv[0])
                        | ((unsigned int)enc_fp8(acc[mf][e2][1] + bv[1]) << 8)
                        | ((unsigned int)enc_fp8(acc[mf][e2][2] + bv[2]) << 16)
                        | ((unsigned int)enc_fp8(acc[mf][e2][3] + bv[3]) << 24);
        *(unsigned int*)(Ts + erow * 128 + ((usw_hi ^ (erow & 7)) << 4) + ulo) = pk;
      }
    }
    __syncthreads();          // Ts visible

    {
      int rr = t >> 1, hh = t & 1;
#pragma unroll
      for (int q = 0; q < 4; ++q){
        int u16 = q * 2 + hh;
        u32x4 v = *(const u32x4*)(Ts + rr * 128 + ((u16 ^ (rr & 7)) << 4));
        *(u32x4*)(E1 + (size_t)(browbase + rr) * 512 + pn * 128 + u16 * 16) = v;
      }
    }
  }
}

// ===========================================================================
// edge_kernel v2: S[n] = sum_{e: dst=n} relu(P1[n] + P2[src] + E1[e]).
// 256 thr = 2 edge-parity groups x (2 batches x 64 col-threads, 8 cols each).
// Each group handles alternate CSR positions (loop halved, loads widened:
// E1 u32x2 = 8B, P2 s16x8 = 16B). Partials combined via 4KB LDS, one barrier.
// ===========================================================================
template<bool USE_P>
__global__ __launch_bounds__(256)
void edge_kernel(const short* __restrict__ P, const unsigned char* __restrict__ E1,
                 const int* __restrict__ csr_src, const int* __restrict__ row_start,
                 short* __restrict__ S)
{
  __shared__ float sm[128][8];            // group-1 partials (4 KB)

  const int n   = blockIdx.x;
  const int t   = threadIdx.x;
  const int hf  = t >> 7;                 // edge-parity group 0/1
  const int tl  = t & 127;                // lane within group
  const int b   = tl >> 6;                // batch
  const int j8  = (tl & 63) * 8;          // 8-col base
  const int ps  = row_start[n], pe = row_start[n + 1];

  float p1c[8];
#pragma unroll
  for (int k = 0; k < 8; ++k) p1c[k] = 0.f;
  if (USE_P){
    s16x8 t1 = *(const s16x8*)(P + (size_t)(n * 2 + b) * 1024 + j8);
#pragma unroll
    for (int k = 0; k < 8; ++k) p1c[k] = bf2f(t1[k]);
  }

  float acc[8];
#pragma unroll
  for (int k = 0; k < 8; ++k) acc[k] = 0.f;

  for (int p = ps + hf; p < pe; p += 2){
    u32x2 ev = *(const u32x2*)(E1 + ((size_t)p * 2 + b) * 512 + j8);
    float e0, e1, e2, e3, e4, e5, e6, e7;
    dec_fp8x4(ev[0], e0, e1, e2, e3);
    dec_fp8x4(ev[1], e4, e5, e6, e7);
    float x[8] = { p1c[0]+e0, p1c[1]+e1, p1c[2]+e2, p1c[3]+e3,
                   p1c[4]+e4, p1c[5]+e5, p1c[6]+e6, p1c[7]+e7 };
    if (USE_P){
      int src = csr_src[p];
      s16x8 pv = *(const s16x8*)(P + (size_t)(src * 2 + b) * 1024 + 512 + j8);
#pragma unroll
      for (int k = 0; k < 8; ++k) x[k] += bf2f(pv[k]);
    }
#pragma unroll
    for (int k = 0; k < 8; ++k) acc[k] += fmaxf(x[k], 0.f);
  }

  // combine group-1 partials into group 0, then store
  if (hf == 1){
#pragma unroll
    for (int k = 0; k < 8; ++k) sm[tl][k] = acc[k];
  }
  __syncthreads();
  if (hf == 0){
    s16x8 o;
#pragma unroll
    for (int k = 0; k < 8; ++k) o[k] = f2bf(acc[k] + sm[tl][k]);
    *(s16x8*)(S + (size_t)(n * 2 + b) * 512 + j8) = o;
  }
}

// ===========================================================================
// node_update (verified R12/R16 version) — staged-B, 512 thr, RB=32,
// LDS 68KB -> 2 blocks/CU. PH0: K=256 gates; PH2: readout.
// ===========================================================================
template<int PH>
__global__ __launch_bounds__(512, 4)
void node_update(const short* __restrict__ S, short* __restrict__ Pout,
                 float* __restrict__ m, float* __restrict__ h,
                 float* __restrict__ g,
                 const short* __restrict__ BtW2, const short* __restrict__ BtRZ,
                 const short* __restrict__ BtHW, const short* __restrict__ BtP,
                 const int* __restrict__ deg, const float* __restrict__ b2,
                 const float* __restrict__ br, const float* __restrict__ bz,
                 const float* __restrict__ bh)
{
  __shared__ __align__(16) char lds[69632];
  short* As = (short*)lds;             // [32][64]   4KB
  short* Bs = (short*)(lds + 4096);    // [256][64] 32KB
  short* Ms = (short*)(lds + 36864);   // [32][256] 16KB
  short* Xs = (short*)(lds + 53248);   // [32][256] 16KB
  float* Hf = (float*)lds;             // [32][256] 32KB overlay (PH2 only)

  const int tid = threadIdx.x;
  const int w = tid >> 6, l = tid & 63;
  const int lr = l & 15, lg = l >> 4;
  const int wq = w >> 2, wc = w & 3;   // row-half, col-quarter
  const int grow0 = blockIdx.x * RB;

  auto stageB = [&](const short* Bt, int K, int pcol0, int k0){
#pragma unroll
    for (int i = 0; i < 4; ++i){
      int u = i * 512 + tid;
      int row = u >> 3, uc = u & 7;
      const short* gp = Bt + (size_t)(pcol0 + row) * K + k0 + ((uc ^ (row & 7)) << 3);
      gload_lds16(gp, (char*)Bs + i * 8192 + w * 1024);
    }
  };
  auto stageA_S = [&](int k0){
    if (w < 4){
      int u = w * 64 + l;
      int row = u >> 3, uc = u & 7;
      const short* gp = S + (size_t)(grow0 + row) * 512 + k0 + ((uc ^ (row & 7)) << 3);
      gload_lds16(gp, (char*)As + w * 1024);
    }
  };
  auto rdA64 = [&](int row, int colel){ return row * 64 + (colel ^ ((row & 7) << 3)); };
  auto rd256 = [&](int row, int colel){ return row * 256 + (colel ^ ((row & 7) << 3)); };

  // ---- h into regs, acc init = m + deg*b2; Xs <- bf16(h) ----
  f32x4 hv[4], acc[4];
#pragma unroll
  for (int j = 0; j < 4; ++j)
#pragma unroll
    for (int r = 0; r < 4; ++r){
      int rl = wq*16 + lg*4 + r, colp = wc*64 + j*16 + lr;
      size_t gi = (size_t)(grow0 + rl) * 256 + colp;
      float base = (float)deg[(grow0 + rl) >> 1] * b2[colp];
      if (PH > 0){ base += m[gi]; hv[j][r] = h[gi]; }
      else hv[j][r] = 0.f;
      acc[j][r] = base;
    }
  if (PH > 0){
#pragma unroll
    for (int j = 0; j < 4; ++j)
#pragma unroll
      for (int r = 0; r < 4; ++r){
        int rl = wq*16 + lg*4 + r, colp = wc*64 + j*16 + lr;
        Xs[rd256(rl, colp)] = f2bf(hv[j][r]);
      }
  }

  // ---- Phase A: acc += S @ W2 (K=512, 8 staged chunks) ----
  for (int c = 0; c < 8; ++c){
    __syncthreads();
    stageA_S(c * 64);
    stageB(BtW2, 512, 0, c * 64);
    __syncthreads();
#pragma unroll
    for (int kk = 0; kk < 2; ++kk){
      s16x8 a0 = *(const s16x8*)(As + rdA64(wq*16 + lr, kk*32 + lg*8));
#pragma unroll
      for (int j = 0; j < 4; ++j){
        s16x8 bb = *(const s16x8*)(Bs + rdA64(wc*64 + j*16 + lr, kk*32 + lg*8));
        acc[j] = MFMA16(a0, bb, acc[j]);
      }
    }
  }
#pragma unroll
  for (int j = 0; j < 4; ++j)
#pragma unroll
    for (int r = 0; r < 4; ++r){
      int rl = wq*16 + lg*4 + r, colp = wc*64 + j*16 + lr;
      float v = acc[j][r];
      if (PH < 2) m[(size_t)(grow0 + rl) * 256 + colp] = v;
      Ms[rd256(rl, colp)] = f2bf(v);
    }

  const int NC = (PH > 0) ? 8 : 4;       // gate K-chunks (PH0: U-half is zero)

  // ---- Phase B: Gr ----
  f32x4 Gr[4], Gz[4];
#pragma unroll
  for (int j = 0; j < 4; ++j){ Gr[j] = (f32x4){0.f,0.f,0.f,0.f}; Gz[j] = (f32x4){0.f,0.f,0.f,0.f}; }

  for (int c = 0; c < NC; ++c){
    __syncthreads();
    stageB(BtRZ, 512, 0, c * 64);
    __syncthreads();
    const short* Ab = (c < 4) ? Ms : Xs;
    int kb = (c & 3) * 64;
#pragma unroll
    for (int kk = 0; kk < 2; ++kk){
      s16x8 a0 = *(const s16x8*)(Ab + rd256(wq*16 + lr, kb + kk*32 + lg*8));
#pragma unroll
      for (int j = 0; j < 4; ++j){
        s16x8 bb = *(const s16x8*)(Bs + rdA64(wc*64 + j*16 + lr, kk*32 + lg*8));
        Gr[j] = MFMA16(a0, bb, Gr[j]);
      }
    }
  }
  // ---- Phase C: Gz ----
  for (int c = 0; c < NC; ++c){
    __syncthreads();
    stageB(BtRZ, 512, 256, c * 64);
    __syncthreads();
    const short* Ab = (c < 4) ? Ms : Xs;
    int kb = (c & 3) * 64;
#pragma unroll
    for (int kk = 0; kk < 2; ++kk){
      s16x8 a0 = *(const s16x8*)(Ab + rd256(wq*16 + lr, kb + kk*32 + lg*8));
#pragma unroll
      for (int j = 0; j < 4; ++j){
        s16x8 bb = *(const s16x8*)(Bs + rdA64(wc*64 + j*16 + lr, kk*32 + lg*8));
        Gz[j] = MFMA16(a0, bb, Gz[j]);
      }
    }
  }

  // ---- e1: r, z; Xs <- bf16(r*h) ----
  f32x4 zz[4];
#pragma unroll
  for (int j = 0; j < 4; ++j)
#pragma unroll
    for (int r = 0; r < 4; ++r){
      int colp = wc*64 + j*16 + lr;
      zz[j][r] = 1.f / (1.f + __expf(-(Gz[j][r] + bz[colp])));
    }
  if (PH > 0){
    __syncthreads();                     // B/C's Xs(hb) reads done
#pragma unroll
    for (int j = 0; j < 4; ++j)
#pragma unroll
      for (int r = 0; r < 4; ++r){
        int rl = wq*16 + lg*4 + r, colp = wc*64 + j*16 + lr;
        float rr = 1.f / (1.f + __expf(-(Gr[j][r] + br[colp])));
        Xs[rd256(rl, colp)] = f2bf(rr * hv[j][r]);
      }
    __syncthreads();                     // Xs(rh) visible
  }

  // ---- Phase D: Gw = [m|rh] @ BtHW ----
  f32x4 Gw[4];
#pragma unroll
  for (int j = 0; j < 4; ++j) Gw[j] = (f32x4){0.f,0.f,0.f,0.f};
  for (int c = 0; c < NC; ++c){
    __syncthreads();
    stageB(BtHW, 512, 0, c * 64);
    __syncthreads();
    const short* Ab = (c < 4) ? Ms : Xs;
    int kb = (c & 3) * 64;
#pragma unroll
    for (int kk = 0; kk < 2; ++kk){
      s16x8 a0 = *(const s16x8*)(Ab + rd256(wq*16 + lr, kb + kk*32 + lg*8));
#pragma unroll
      for (int j = 0; j < 4; ++j){
        s16x8 bb = *(const s16x8*)(Bs + rdA64(wc*64 + j*16 + lr, kk*32 + lg*8));
        Gw[j] = MFMA16(a0, bb, Gw[j]);
      }
    }
  }

  // ---- e2: h' ----
  __syncthreads();                       // D's Ms/Xs reads done
#pragma unroll
  for (int j = 0; j < 4; ++j)
#pragma unroll
    for (int r = 0; r < 4; ++r){
      int rl = wq*16 + lg*4 + r, colp = wc*64 + j*16 + lr;
      float ht = tanhf(Gw[j][r] + bh[colp]);
      float z  = zz[j][r];
      float hn = (1.f - z) * hv[j][r] + z * ht;
      if (PH < 2){
        h[(size_t)(grow0 + rl) * 256 + colp] = hn;
        Ms[rd256(rl, colp)] = f2bf(hn);
      } else {
        Hf[rl * 256 + colp] = hn;
      }
    }
  __syncthreads();                       // Ms(h') / Hf visible

  if (PH < 2){
    // ---- Phase E: P = h' @ BtP, 4 panels of 256 cols ----
    for (int pn = 0; pn < 4; ++pn){
      f32x4 pa[4];
#pragma unroll
      for (int j = 0; j < 4; ++j) pa[j] = (f32x4){0.f,0.f,0.f,0.f};
      for (int c = 0; c < 4; ++c){
        __syncthreads();
        stageB(BtP, 256, pn * 256, c * 64);
        __syncthreads();
#pragma unroll
        for (int kk = 0; kk < 2; ++kk){
          s16x8 a0 = *(const s16x8*)(Ms + rd256(wq*16 + lr, c*64 + kk*32 + lg*8));
#pragma unroll
          for (int j = 0; j < 4; ++j){
            s16x8 bb = *(const s16x8*)(Bs + rdA64(wc*64 + j*16 + lr, kk*32 + lg*8));
            pa[j] = MFMA16(a0, bb, pa[j]);
          }
        }
      }
#pragma unroll
      for (int j = 0; j < 4; ++j)
#pragma unroll
        for (int r = 0; r < 4; ++r){
          int colp = wc*64 + j*16 + lr;
          Pout[(size_t)(grow0 + wq*16 + lg*4 + r) * 1024 + pn*256 + colp] = f2bf(pa[j][r]);
        }
    }
  } else {
    // ---- readout partial: g[b*256+c] += sum rows ----
    int col = tid & 255, pb = (tid >> 8) & 1;
    float s = 0.f;
#pragma unroll
    for (int rr = 0; rr < 16; ++rr)
      s += Hf[(2*rr + pb) * 256 + col];
    atomicAdd(&g[pb * 256 + col], s);
  }
}

// ------------------------------- CSR build ---------------------------------
__global__ void count_kernel(const int* __restrict__ edst, int* __restrict__ counts){
  int e = blockIdx.x * 256 + threadIdx.x;
  if (e < E_EDGES) atomicAdd(&counts[edst[e]], 1);
}
__global__ void scan_kernel(const int* __restrict__ counts, int* __restrict__ row_start,
                            int* __restrict__ cursor){
  __shared__ int sums[1024];
  int t = threadIdx.x;
  int base = t * 8;
  int loc[8]; int s = 0;
#pragma unroll
  for (int i = 0; i < 8; ++i){ loc[i] = s; s += counts[base + i]; }
  sums[t] = s;
  __syncthreads();
  for (int o = 1; o < 1024; o <<= 1){
    int v = sums[t];
    int u = (t >= o) ? sums[t - o] : 0;
    __syncthreads();
    sums[t] = v + u;
    __syncthreads();
  }
  int excl = (t == 0) ? 0 : sums[t - 1];
#pragma unroll
  for (int i = 0; i < 8; ++i){ int v = excl + loc[i]; row_start[base + i] = v; cursor[base + i] = v; }
  if (t == 1023) row_start[NNODES] = sums[1023];
}
__global__ void fill_kernel(const int* __restrict__ edst, const int* __restrict__ esrc,
                            int* __restrict__ cursor, int* __restrict__ csr_eid,
                            int* __restrict__ csr_src){
  int e = blockIdx.x * 256 + threadIdx.x;
  if (e < E_EDGES){
    int pos = atomicAdd(&cursor[edst[e]], 1);
    csr_eid[pos] = e;
    csr_src[pos] = esrc[e];
  }
}

// --------------------------- weight repacking ------------------------------
// BtP [1024][256], BtE [512][64] PRE-SWIZZLED, BtW2 [256][512],
// BtRZ [512][512] (cols r|z, K = W|U), BtHW [256][512] (K = Wh|Uh)
__global__ void prep_weights(const float* __restrict__ W1, const float* __restrict__ W2,
                             const float* __restrict__ Wr, const float* __restrict__ Ur,
                             const float* __restrict__ Wz, const float* __restrict__ Uz,
                             const float* __restrict__ Wh, const float* __restrict__ Uh,
                             short* __restrict__ BtP, short* __restrict__ BtE,
                             short* __restrict__ BtW2, short* __restrict__ BtRZ,
                             short* __restrict__ BtHW)
{
  int id = blockIdx.x * 256 + threadIdx.x;
  if (id < 262144){                       // BtP
    int jj = id >> 8, k = id & 255;
    float v = (jj < 512) ? W1[(size_t)k * 512 + jj] : W1[(size_t)(256 + k) * 512 + (jj - 512)];
    BtP[id] = f2bf(v);
  } else if (id < 294912){                // BtE pre-swizzled
    int i2 = id - 262144; int jj = i2 >> 6, c = i2 & 63;
    BtE[jj * 64 + (c ^ ((jj & 7) << 3))] = f2bf(W1[(size_t)(512 + c) * 512 + jj]);
  } else if (id < 425984){                // BtW2
    int i2 = id - 294912; int n = i2 >> 9, k = i2 & 511;
    BtW2[i2] = f2bf(W2[(size_t)k * 256 + n]);
  } else if (id < 688128){                // BtRZ
    int i2 = id - 425984; int col = i2 >> 9, k = i2 & 511;
    float v;
    if (col < 256) v = (k < 256) ? Wr[(size_t)k * 256 + col] : Ur[(size_t)(k - 256) * 256 + col];
    else { int c2 = col - 256; v = (k < 256) ? Wz[(size_t)k * 256 + c2] : Uz[(size_t)(k - 256) * 256 + c2]; }
    BtRZ[i2] = f2bf(v);
  } else if (id < 819200){                // BtHW
    int i2 = id - 688128; int col = i2 >> 9, k = i2 & 511;
    float v = (k < 256) ? Wh[(size_t)k * 256 + col] : Uh[(size_t)(k - 256) * 256 + col];
    BtHW[i2] = f2bf(v);
  }
}

// -------------------------------- readout ----------------------------------
__global__ __launch_bounds__(256)
void readout2(const float* __restrict__ g, const float* __restrict__ Wo,
              const float* __restrict__ bo, float* __restrict__ out){
  int t = threadIdx.x;
  int b = t >> 7, o = t & 127;
  float s = bo[o];
  for (int c = 0; c < 256; ++c) s += g[b * 256 + c] * Wo[c * 128 + o];
  out[b * 128 + o] = s;
}

// ===========================================================================
extern "C" void kernel_launch(void* const* d_in, const int* in_sizes, int n_in,
                              void* d_out, int out_size, void* d_ws, size_t ws_size,
                              hipStream_t stream)
{
  const float* ef  = (const float*)d_in[0];
  const float* W1  = (const float*)d_in[1];
  const float* b1  = (const float*)d_in[2];
  const float* W2  = (const float*)d_in[3];
  const float* b2  = (const float*)d_in[4];
  const float* Wr  = (const float*)d_in[5];
  const float* Ur  = (const float*)d_in[6];
  const float* br  = (const float*)d_in[7];
  const float* Wz  = (const float*)d_in[8];
  const float* Uz  = (const float*)d_in[9];
  const float* bz  = (const float*)d_in[10];
  const float* Wh  = (const float*)d_in[11];
  const float* Uh  = (const float*)d_in[12];
  const float* bh  = (const float*)d_in[13];
  const float* Wo  = (const float*)d_in[14];
  const float* bo  = (const float*)d_in[15];
  const int* esrc  = (const int*)d_in[16];
  const int* edst  = (const int*)d_in[17];

  char* base = (char*)d_ws;
  size_t off = 0;
  auto alloc = [&](size_t bytes) -> char* {
    off = (off + 255) & ~(size_t)255;
    char* p = base + off;
    off += bytes;
    return p;
  };
  float* h    = (float*)alloc((size_t)NB * 256 * 4);            // 16 MB
  float* m    = (float*)alloc((size_t)NB * 256 * 4);            // 16 MB
  short* P    = (short*)alloc((size_t)NB * 1024 * 2);           // 32 MB
  short* S    = (short*)alloc((size_t)NB * 512 * 2);            // 16 MB
  unsigned char* E1 = (unsigned char*)alloc((size_t)E_EDGES * 2 * MLPH); // 128 MiB
  short* BtP  = (short*)alloc(262144 * 2);
  short* BtE  = (short*)alloc(32768 * 2);
  short* BtW2 = (short*)alloc(131072 * 2);
  short* BtRZ = (short*)alloc(262144 * 2);
  short* BtHW = (short*)alloc(131072 * 2);
  int* counts = (int*)alloc(NNODES * 4);
  int* rs     = (int*)alloc((NNODES + 1) * 4);
  int* cursor = (int*)alloc(NNODES * 4);
  int* ceid   = (int*)alloc(E_EDGES * 4);
  int* csrc   = (int*)alloc(E_EDGES * 4);
  float* g    = (float*)alloc(512 * 4);
  // total ~216 MB < 256 MiB workspace

  dim3 blk(256);

  // ------------------------------- prep ----------------------------------
  hipMemsetAsync(g,  0, 512 * 4, stream);
  hipMemsetAsync(counts, 0, NNODES * 4, stream);
  prep_weights<<<3200, blk, 0, stream>>>(W1, W2, Wr, Ur, Wz, Uz, Wh, Uh,
                                         BtP, BtE, BtW2, BtRZ, BtHW);
  count_kernel<<<512, blk, 0, stream>>>(edst, counts);
  scan_kernel<<<1, 1024, 0, stream>>>(counts, rs, cursor);
  fill_kernel<<<512, blk, 0, stream>>>(edst, esrc, cursor, ceid, csrc);

  // E1 (fp8) computed ONCE — iteration-invariant
  e1_gemm<<<E_EDGES * 2 / 128, blk, 0, stream>>>(ef, BtE, E1, b1, ceid);

  // ----------------------------- iterations ------------------------------
  edge_kernel<false><<<NNODES, blk, 0, stream>>>(P, E1, csrc, rs, S);
  node_update<0><<<NB / RB, dim3(512), 0, stream>>>(S, P, m, h, g,
      BtW2, BtRZ, BtHW, BtP, counts, b2, br, bz, bh);

  edge_kernel<true><<<NNODES, blk, 0, stream>>>(P, E1, csrc, rs, S);
  node_update<1><<<NB / RB, dim3(512), 0, stream>>>(S, P, m, h, g,
      BtW2, BtRZ, BtHW, BtP, counts, b2, br, bz, bh);

  edge_kernel<true><<<NNODES, blk, 0, stream>>>(P, E1, csrc, rs, S);
  node_update<2><<<NB / RB, dim3(512), 0, stream>>>(S, P, m, h, g,
      BtW2, BtRZ, BtHW, BtP, counts, b2, br, bz, bh);

  // ------------------------------ readout --------------------------------
  readout2<<<1, blk, 0, stream>>>(g, Wo, bo, (float*)d_out);
}

// Round 18
// 407.447 us; speedup vs baseline: 1.0770x; 1.0034x over previous
//
#include <hip/hip_runtime.h>
#include <hip/hip_bf16.h>

#define E_EDGES 131072
#define NNODES  8192
#define NB      16384   // N_NODES * BATCH rows
#define HID     256
#define EDIM    64
#define MLPH    512
#define OUTD    128
#define NIT     3
#define RB      32      // rows per node_update block

typedef short s16x4 __attribute__((ext_vector_type(4)));
typedef short s16x8 __attribute__((ext_vector_type(8)));
typedef float f32x4 __attribute__((ext_vector_type(4)));
typedef float f32x2 __attribute__((ext_vector_type(2)));
typedef unsigned int u32x2 __attribute__((ext_vector_type(2)));
typedef unsigned int u32x4 __attribute__((ext_vector_type(4)));

__device__ __forceinline__ short f2bf(float f){
  unsigned int x = __builtin_bit_cast(unsigned int, f);
  x += 0x7fffu + ((x >> 16) & 1u);          // RNE
  return (short)(x >> 16);
}
__device__ __forceinline__ float bf2f(short s){
  unsigned int x = ((unsigned int)(unsigned short)s) << 16;
  return __builtin_bit_cast(float, x);
}
__device__ __forceinline__ void gload_lds16(const void* g, void* l){
  __builtin_amdgcn_global_load_lds(
      (const __attribute__((address_space(1))) void*)g,
      (__attribute__((address_space(3))) void*)l, 16, 0, 0);
}
#define MFMA16(a,b,c) __builtin_amdgcn_mfma_f32_16x16x32_bf16((a),(b),(c),0,0,0)

// ---------------- fp8 (e4m3-style) encode/decode ----------------
#if defined(__has_builtin)
#if __has_builtin(__builtin_amdgcn_cvt_pk_f32_fp8) && __has_builtin(__builtin_amdgcn_cvt_pk_fp8_f32)
#define FP8_HW 1
#endif
#endif
#ifndef FP8_HW
#define FP8_HW 0
#endif

__device__ __forceinline__ unsigned char enc_fp8_sw(float f){
  unsigned int b = __builtin_bit_cast(unsigned int, f);
  unsigned int s = (b >> 24) & 0x80u;
  float a = fabsf(f);
  if (a >= 448.f) return (unsigned char)(s | 0x7e);       // clamp to 448
  if (a < 0.015625f){                                      // denorm: m*2^-9
    int q = (int)rintf(a * 512.f);                         // 0..8
    return (unsigned char)(s | (unsigned int)q);           // q==8 -> e=1,m=0
  }
  unsigned int e32  = (b >> 23) & 0xff;
  unsigned int mant = b & 0x7fffff;
  unsigned int rnd  = mant + 0x7ffff + ((mant >> 20) & 1); // RNE at bit 20
  unsigned int e8   = e32 - 120 + (rnd >> 23);
  unsigned int m3   = (rnd >> 20) & 7;
  if (e8 >= 16) return (unsigned char)(s | 0x7e);
  return (unsigned char)(s | (e8 << 3) | m3);
}
__device__ __forceinline__ float dec_fp8_sw(unsigned int v){
  unsigned int s = (v >> 7) & 1, e = (v >> 3) & 15, m = v & 7;
  float r;
  if (e == 0) r = (float)m * 0.001953125f;                 // m * 2^-9
  else        r = __builtin_bit_cast(float, ((e + 120u) << 23) | (m << 20));
  return s ? -r : r;
}
__device__ __forceinline__ unsigned char enc_fp8(float f){
#if FP8_HW
  unsigned int pk = (unsigned int)__builtin_amdgcn_cvt_pk_fp8_f32(f, f, 0, false);
  return (unsigned char)(pk & 0xff);
#else
  return enc_fp8_sw(f);
#endif
}
__device__ __forceinline__ void dec_fp8x4(unsigned int ev, float& e0, float& e1,
                                          float& e2, float& e3){
#if FP8_HW
  f32x2 lo = __builtin_amdgcn_cvt_pk_f32_fp8((int)ev, false);
  f32x2 hi = __builtin_amdgcn_cvt_pk_f32_fp8((int)ev, true);
  e0 = lo[0]; e1 = lo[1]; e2 = hi[0]; e3 = hi[1];
#else
  e0 = dec_fp8_sw(ev & 0xff); e1 = dec_fp8_sw((ev >> 8) & 0xff);
  e2 = dec_fp8_sw((ev >> 16) & 0xff); e3 = dec_fp8_sw(ev >> 24);
#endif
}

// ===========================================================================
// e1_gemm v3 (verified R12) — runs ONCE.
// ===========================================================================
__global__ __launch_bounds__(256, 3)
void e1_gemm(const float* __restrict__ ef, const short* __restrict__ BtE,
             unsigned char* __restrict__ E1, const float* __restrict__ b1,
             const int* __restrict__ ceid)
{
  __shared__ __align__(16) short As[128 * 64];          // 16 KB swizzled
  __shared__ __align__(16) short Bs[128 * 64];          // 16 KB swizzled
  __shared__ __align__(16) unsigned char Ts[128 * 128]; // 16 KB out panel

  const int t  = threadIdx.x;
  const int w  = t >> 6, l = t & 63;
  const int lr = l & 15, lg = l >> 4;
  const int wr = w >> 1, wc = w & 1;
  const int browbase = blockIdx.x * 128;
  const int srow = t >> 3;
  const int scol = (t & 7) * 8;

#pragma unroll
  for (int i = 0; i < 4; ++i){
    int R = browbase + srow + i * 32;
    int e = ceid[R >> 1];
    const float* ap = ef + ((size_t)e * 2 + (R & 1)) * EDIM + scol;
    f32x4 f0 = *(const f32x4*)ap;
    f32x4 f1 = *(const f32x4*)(ap + 4);
    s16x8 o;
    o[0]=f2bf(f0[0]); o[1]=f2bf(f0[1]); o[2]=f2bf(f0[2]); o[3]=f2bf(f0[3]);
    o[4]=f2bf(f1[0]); o[5]=f2bf(f1[1]); o[6]=f2bf(f1[2]); o[7]=f2bf(f1[3]);
    int row = srow + i * 32;
    *(s16x8*)(As + row * 64 + (scol ^ ((row & 7) << 3))) = o;
  }

  for (int pn = 0; pn < 4; ++pn){
#pragma unroll
    for (int i = 0; i < 4; ++i)
      gload_lds16(BtE + (size_t)(pn * 128 + srow + i * 32) * 64 + scol,
                  (char*)Bs + w * 1024 + i * 4096);
    __syncthreads();          // As+Bs staged; prev panel's Ts reads done

    f32x4 acc[4][4];
#pragma unroll
    for (int mf = 0; mf < 4; ++mf)
#pragma unroll
      for (int e2 = 0; e2 < 4; ++e2) acc[mf][e2] = (f32x4){0.f,0.f,0.f,0.f};

#pragma unroll
    for (int kk = 0; kk < 2; ++kk){
      s16x8 a[4], b[4];
#pragma unroll
      for (int e2 = 0; e2 < 4; ++e2){
        int ar = wr*64 + e2*16 + lr;
        a[e2] = *(const s16x8*)(As + ar * 64 + ((kk*32 + lg*8) ^ ((ar & 7) << 3)));
      }
#pragma unroll
      for (int mf = 0; mf < 4; ++mf){
        int br = wc*64 + mf*16 + lr;
        b[mf] = *(const s16x8*)(Bs + br * 64 + ((kk*32 + lg*8) ^ ((br & 7) << 3)));
      }
#pragma unroll
      for (int mf = 0; mf < 4; ++mf)
#pragma unroll
        for (int e2 = 0; e2 < 4; ++e2)
          acc[mf][e2] = MFMA16(b[mf], a[e2], acc[mf][e2]);   // swapped
    }

#pragma unroll
    for (int mf = 0; mf < 4; ++mf){
      int mloc = wc*64 + mf*16 + lg*4;
      f32x4 bv = *(const f32x4*)(b1 + pn*128 + mloc);
      int u = mloc >> 2;
      int usw_hi = (u >> 2), ulo = (u & 3) << 2;
#pragma unroll
      for (int e2 = 0; e2 < 4; ++e2){
        int erow = wr*64 + e2*16 + lr;
        unsigned int pk = (unsigned int)enc_fp8(acc[mf][e2][0] + bv[0])
                        | ((unsigned int)enc_fp8(acc[mf][e2][1] + bv[1]) << 8)
                        | ((unsigned int)enc_fp8(acc[mf][e2][2] + bv[2]) << 16)
                        | ((unsigned int)enc_fp8(acc[mf][e2][3] + bv[3]) << 24);
        *(unsigned int*)(Ts + erow * 128 + ((usw_hi ^ (erow & 7)) << 4) + ulo) = pk;
      }
    }
    __syncthreads();          // Ts visible

    {
      int rr = t >> 1, hh = t & 1;
#pragma unroll
      for (int q = 0; q < 4; ++q){
        int u16 = q * 2 + hh;
        u32x4 v = *(const u32x4*)(Ts + rr * 128 + ((u16 ^ (rr & 7)) << 4));
        *(u32x4*)(E1 + (size_t)(browbase + rr) * 512 + pn * 128 + u16 * 16) = v;
      }
    }
  }
}

// ===========================================================================
// edge_kernel v3: S[n] = sum_{e: dst=n} relu(P1[n] + P2[src] + E1[e]).
// 256 thr = 4 edge-parity groups x (2 batches x 32 col-threads, 16 cols).
// Per-thread loop = deg/4; loads: E1 u32x4 (16B) + P2 2x s16x8 (32B).
// Groups 1-3 deposit partials in LDS (12KB); group 0 combines + stores.
// ===========================================================================
template<bool USE_P>
__global__ __launch_bounds__(256)
void edge_kernel(const short* __restrict__ P, const unsigned char* __restrict__ E1,
                 const int* __restrict__ csr_src, const int* __restrict__ row_start,
                 short* __restrict__ S)
{
  __shared__ float sm[3][64][16];         // groups 1..3 partials (12 KB)

  const int n   = blockIdx.x;
  const int t   = threadIdx.x;
  const int hf  = t >> 6;                 // edge-parity group 0..3
  const int tl  = t & 63;                 // lane within group
  const int b   = tl >> 5;                // batch
  const int j16 = (tl & 31) * 16;         // 16-col base
  const int ps  = row_start[n], pe = row_start[n + 1];

  float p1c[16];
#pragma unroll
  for (int k = 0; k < 16; ++k) p1c[k] = 0.f;
  if (USE_P){
    s16x8 t0 = *(const s16x8*)(P + (size_t)(n * 2 + b) * 1024 + j16);
    s16x8 t1 = *(const s16x8*)(P + (size_t)(n * 2 + b) * 1024 + j16 + 8);
#pragma unroll
    for (int k = 0; k < 8; ++k){ p1c[k] = bf2f(t0[k]); p1c[8 + k] = bf2f(t1[k]); }
  }

  float acc[16];
#pragma unroll
  for (int k = 0; k < 16; ++k) acc[k] = 0.f;

  for (int p = ps + hf; p < pe; p += 4){
    u32x4 ev = *(const u32x4*)(E1 + ((size_t)p * 2 + b) * 512 + j16);
    float x[16];
    dec_fp8x4(ev[0], x[0],  x[1],  x[2],  x[3]);
    dec_fp8x4(ev[1], x[4],  x[5],  x[6],  x[7]);
    dec_fp8x4(ev[2], x[8],  x[9],  x[10], x[11]);
    dec_fp8x4(ev[3], x[12], x[13], x[14], x[15]);
#pragma unroll
    for (int k = 0; k < 16; ++k) x[k] += p1c[k];
    if (USE_P){
      int src = csr_src[p];
      const short* p2r = P + (size_t)(src * 2 + b) * 1024 + 512 + j16;
      s16x8 v0 = *(const s16x8*)p2r;
      s16x8 v1 = *(const s16x8*)(p2r + 8);
#pragma unroll
      for (int k = 0; k < 8; ++k){ x[k] += bf2f(v0[k]); x[8 + k] += bf2f(v1[k]); }
    }
#pragma unroll
    for (int k = 0; k < 16; ++k) acc[k] += fmaxf(x[k], 0.f);
  }

  if (hf > 0){
#pragma unroll
    for (int k = 0; k < 16; ++k) sm[hf - 1][tl][k] = acc[k];
  }
  __syncthreads();
  if (hf == 0){
    s16x8 o0, o1;
#pragma unroll
    for (int k = 0; k < 8; ++k){
      float v0 = acc[k]     + sm[0][tl][k]     + sm[1][tl][k]     + sm[2][tl][k];
      float v1 = acc[8 + k] + sm[0][tl][8 + k] + sm[1][tl][8 + k] + sm[2][tl][8 + k];
      o0[k] = f2bf(v0); o1[k] = f2bf(v1);
    }
    *(s16x8*)(S + (size_t)(n * 2 + b) * 512 + j16)     = o0;
    *(s16x8*)(S + (size_t)(n * 2 + b) * 512 + j16 + 8) = o1;
  }
}

// ===========================================================================
// node_update (verified R12/R16 version) — staged-B, 512 thr, RB=32,
// LDS 68KB -> 2 blocks/CU. PH0: K=256 gates; PH2: readout.
// ===========================================================================
template<int PH>
__global__ __launch_bounds__(512, 4)
void node_update(const short* __restrict__ S, short* __restrict__ Pout,
                 float* __restrict__ m, float* __restrict__ h,
                 float* __restrict__ g,
                 const short* __restrict__ BtW2, const short* __restrict__ BtRZ,
                 const short* __restrict__ BtHW, const short* __restrict__ BtP,
                 const int* __restrict__ deg, const float* __restrict__ b2,
                 const float* __restrict__ br, const float* __restrict__ bz,
                 const float* __restrict__ bh)
{
  __shared__ __align__(16) char lds[69632];
  short* As = (short*)lds;             // [32][64]   4KB
  short* Bs = (short*)(lds + 4096);    // [256][64] 32KB
  short* Ms = (short*)(lds + 36864);   // [32][256] 16KB
  short* Xs = (short*)(lds + 53248);   // [32][256] 16KB
  float* Hf = (float*)lds;             // [32][256] 32KB overlay (PH2 only)

  const int tid = threadIdx.x;
  const int w = tid >> 6, l = tid & 63;
  const int lr = l & 15, lg = l >> 4;
  const int wq = w >> 2, wc = w & 3;   // row-half, col-quarter
  const int grow0 = blockIdx.x * RB;

  auto stageB = [&](const short* Bt, int K, int pcol0, int k0){
#pragma unroll
    for (int i = 0; i < 4; ++i){
      int u = i * 512 + tid;
      int row = u >> 3, uc = u & 7;
      const short* gp = Bt + (size_t)(pcol0 + row) * K + k0 + ((uc ^ (row & 7)) << 3);
      gload_lds16(gp, (char*)Bs + i * 8192 + w * 1024);
    }
  };
  auto stageA_S = [&](int k0){
    if (w < 4){
      int u = w * 64 + l;
      int row = u >> 3, uc = u & 7;
      const short* gp = S + (size_t)(grow0 + row) * 512 + k0 + ((uc ^ (row & 7)) << 3);
      gload_lds16(gp, (char*)As + w * 1024);
    }
  };
  auto rdA64 = [&](int row, int colel){ return row * 64 + (colel ^ ((row & 7) << 3)); };
  auto rd256 = [&](int row, int colel){ return row * 256 + (colel ^ ((row & 7) << 3)); };

  // ---- h into regs, acc init = m + deg*b2; Xs <- bf16(h) ----
  f32x4 hv[4], acc[4];
#pragma unroll
  for (int j = 0; j < 4; ++j)
#pragma unroll
    for (int r = 0; r < 4; ++r){
      int rl = wq*16 + lg*4 + r, colp = wc*64 + j*16 + lr;
      size_t gi = (size_t)(grow0 + rl) * 256 + colp;
      float base = (float)deg[(grow0 + rl) >> 1] * b2[colp];
      if (PH > 0){ base += m[gi]; hv[j][r] = h[gi]; }
      else hv[j][r] = 0.f;
      acc[j][r] = base;
    }
  if (PH > 0){
#pragma unroll
    for (int j = 0; j < 4; ++j)
#pragma unroll
      for (int r = 0; r < 4; ++r){
        int rl = wq*16 + lg*4 + r, colp = wc*64 + j*16 + lr;
        Xs[rd256(rl, colp)] = f2bf(hv[j][r]);
      }
  }

  // ---- Phase A: acc += S @ W2 (K=512, 8 staged chunks) ----
  for (int c = 0; c < 8; ++c){
    __syncthreads();
    stageA_S(c * 64);
    stageB(BtW2, 512, 0, c * 64);
    __syncthreads();
#pragma unroll
    for (int kk = 0; kk < 2; ++kk){
      s16x8 a0 = *(const s16x8*)(As + rdA64(wq*16 + lr, kk*32 + lg*8));
#pragma unroll
      for (int j = 0; j < 4; ++j){
        s16x8 bb = *(const s16x8*)(Bs + rdA64(wc*64 + j*16 + lr, kk*32 + lg*8));
        acc[j] = MFMA16(a0, bb, acc[j]);
      }
    }
  }
#pragma unroll
  for (int j = 0; j < 4; ++j)
#pragma unroll
    for (int r = 0; r < 4; ++r){
      int rl = wq*16 + lg*4 + r, colp = wc*64 + j*16 + lr;
      float v = acc[j][r];
      if (PH < 2) m[(size_t)(grow0 + rl) * 256 + colp] = v;
      Ms[rd256(rl, colp)] = f2bf(v);
    }

  const int NC = (PH > 0) ? 8 : 4;       // gate K-chunks (PH0: U-half is zero)

  // ---- Phase B: Gr ----
  f32x4 Gr[4], Gz[4];
#pragma unroll
  for (int j = 0; j < 4; ++j){ Gr[j] = (f32x4){0.f,0.f,0.f,0.f}; Gz[j] = (f32x4){0.f,0.f,0.f,0.f}; }

  for (int c = 0; c < NC; ++c){
    __syncthreads();
    stageB(BtRZ, 512, 0, c * 64);
    __syncthreads();
    const short* Ab = (c < 4) ? Ms : Xs;
    int kb = (c & 3) * 64;
#pragma unroll
    for (int kk = 0; kk < 2; ++kk){
      s16x8 a0 = *(const s16x8*)(Ab + rd256(wq*16 + lr, kb + kk*32 + lg*8));
#pragma unroll
      for (int j = 0; j < 4; ++j){
        s16x8 bb = *(const s16x8*)(Bs + rdA64(wc*64 + j*16 + lr, kk*32 + lg*8));
        Gr[j] = MFMA16(a0, bb, Gr[j]);
      }
    }
  }
  // ---- Phase C: Gz ----
  for (int c = 0; c < NC; ++c){
    __syncthreads();
    stageB(BtRZ, 512, 256, c * 64);
    __syncthreads();
    const short* Ab = (c < 4) ? Ms : Xs;
    int kb = (c & 3) * 64;
#pragma unroll
    for (int kk = 0; kk < 2; ++kk){
      s16x8 a0 = *(const s16x8*)(Ab + rd256(wq*16 + lr, kb + kk*32 + lg*8));
#pragma unroll
      for (int j = 0; j < 4; ++j){
        s16x8 bb = *(const s16x8*)(Bs + rdA64(wc*64 + j*16 + lr, kk*32 + lg*8));
        Gz[j] = MFMA16(a0, bb, Gz[j]);
      }
    }
  }

  // ---- e1: r, z; Xs <- bf16(r*h) ----
  f32x4 zz[4];
#pragma unroll
  for (int j = 0; j < 4; ++j)
#pragma unroll
    for (int r = 0; r < 4; ++r){
      int colp = wc*64 + j*16 + lr;
      zz[j][r] = 1.f / (1.f + __expf(-(Gz[j][r] + bz[colp])));
    }
  if (PH > 0){
    __syncthreads();                     // B/C's Xs(hb) reads done
#pragma unroll
    for (int j = 0; j < 4; ++j)
#pragma unroll
      for (int r = 0; r < 4; ++r){
        int rl = wq*16 + lg*4 + r, colp = wc*64 + j*16 + lr;
        float rr = 1.f / (1.f + __expf(-(Gr[j][r] + br[colp])));
        Xs[rd256(rl, colp)] = f2bf(rr * hv[j][r]);
      }
    __syncthreads();                     // Xs(rh) visible
  }

  // ---- Phase D: Gw = [m|rh] @ BtHW ----
  f32x4 Gw[4];
#pragma unroll
  for (int j = 0; j < 4; ++j) Gw[j] = (f32x4){0.f,0.f,0.f,0.f};
  for (int c = 0; c < NC; ++c){
    __syncthreads();
    stageB(BtHW, 512, 0, c * 64);
    __syncthreads();
    const short* Ab = (c < 4) ? Ms : Xs;
    int kb = (c & 3) * 64;
#pragma unroll
    for (int kk = 0; kk < 2; ++kk){
      s16x8 a0 = *(const s16x8*)(Ab + rd256(wq*16 + lr, kb + kk*32 + lg*8));
#pragma unroll
      for (int j = 0; j < 4; ++j){
        s16x8 bb = *(const s16x8*)(Bs + rdA64(wc*64 + j*16 + lr, kk*32 + lg*8));
        Gw[j] = MFMA16(a0, bb, Gw[j]);
      }
    }
  }

  // ---- e2: h' ----
  __syncthreads();                       // D's Ms/Xs reads done
#pragma unroll
  for (int j = 0; j < 4; ++j)
#pragma unroll
    for (int r = 0; r < 4; ++r){
      int rl = wq*16 + lg*4 + r, colp = wc*64 + j*16 + lr;
      float ht = tanhf(Gw[j][r] + bh[colp]);
      float z  = zz[j][r];
      float hn = (1.f - z) * hv[j][r] + z * ht;
      if (PH < 2){
        h[(size_t)(grow0 + rl) * 256 + colp] = hn;
        Ms[rd256(rl, colp)] = f2bf(hn);
      } else {
        Hf[rl * 256 + colp] = hn;
      }
    }
  __syncthreads();                       // Ms(h') / Hf visible

  if (PH < 2){
    // ---- Phase E: P = h' @ BtP, 4 panels of 256 cols ----
    for (int pn = 0; pn < 4; ++pn){
      f32x4 pa[4];
#pragma unroll
      for (int j = 0; j < 4; ++j) pa[j] = (f32x4){0.f,0.f,0.f,0.f};
      for (int c = 0; c < 4; ++c){
        __syncthreads();
        stageB(BtP, 256, pn * 256, c * 64);
        __syncthreads();
#pragma unroll
        for (int kk = 0; kk < 2; ++kk){
          s16x8 a0 = *(const s16x8*)(Ms + rd256(wq*16 + lr, c*64 + kk*32 + lg*8));
#pragma unroll
          for (int j = 0; j < 4; ++j){
            s16x8 bb = *(const s16x8*)(Bs + rdA64(wc*64 + j*16 + lr, kk*32 + lg*8));
            pa[j] = MFMA16(a0, bb, pa[j]);
          }
        }
      }
#pragma unroll
      for (int j = 0; j < 4; ++j)
#pragma unroll
        for (int r = 0; r < 4; ++r){
          int colp = wc*64 + j*16 + lr;
          Pout[(size_t)(grow0 + wq*16 + lg*4 + r) * 1024 + pn*256 + colp] = f2bf(pa[j][r]);
        }
    }
  } else {
    // ---- readout partial: g[b*256+c] += sum rows ----
    int col = tid & 255, pb = (tid >> 8) & 1;
    float s = 0.f;
#pragma unroll
    for (int rr = 0; rr < 16; ++rr)
      s += Hf[(2*rr + pb) * 256 + col];
    atomicAdd(&g[pb * 256 + col], s);
  }
}

// ------------------------------- CSR build ---------------------------------
__global__ void count_kernel(const int* __restrict__ edst, int* __restrict__ counts){
  int e = blockIdx.x * 256 + threadIdx.x;
  if (e < E_EDGES) atomicAdd(&counts[edst[e]], 1);
}
__global__ void scan_kernel(const int* __restrict__ counts, int* __restrict__ row_start,
                            int* __restrict__ cursor){
  __shared__ int sums[1024];
  int t = threadIdx.x;
  int base = t * 8;
  int loc[8]; int s = 0;
#pragma unroll
  for (int i = 0; i < 8; ++i){ loc[i] = s; s += counts[base + i]; }
  sums[t] = s;
  __syncthreads();
  for (int o = 1; o < 1024; o <<= 1){
    int v = sums[t];
    int u = (t >= o) ? sums[t - o] : 0;
    __syncthreads();
    sums[t] = v + u;
    __syncthreads();
  }
  int excl = (t == 0) ? 0 : sums[t - 1];
#pragma unroll
  for (int i = 0; i < 8; ++i){ int v = excl + loc[i]; row_start[base + i] = v; cursor[base + i] = v; }
  if (t == 1023) row_start[NNODES] = sums[1023];
}
__global__ void fill_kernel(const int* __restrict__ edst, const int* __restrict__ esrc,
                            int* __restrict__ cursor, int* __restrict__ csr_eid,
                            int* __restrict__ csr_src){
  int e = blockIdx.x * 256 + threadIdx.x;
  if (e < E_EDGES){
    int pos = atomicAdd(&cursor[edst[e]], 1);
    csr_eid[pos] = e;
    csr_src[pos] = esrc[e];
  }
}

// --------------------------- weight repacking ------------------------------
// BtP [1024][256], BtE [512][64] PRE-SWIZZLED, BtW2 [256][512],
// BtRZ [512][512] (cols r|z, K = W|U), BtHW [256][512] (K = Wh|Uh)
__global__ void prep_weights(const float* __restrict__ W1, const float* __restrict__ W2,
                             const float* __restrict__ Wr, const float* __restrict__ Ur,
                             const float* __restrict__ Wz, const float* __restrict__ Uz,
                             const float* __restrict__ Wh, const float* __restrict__ Uh,
                             short* __restrict__ BtP, short* __restrict__ BtE,
                             short* __restrict__ BtW2, short* __restrict__ BtRZ,
                             short* __restrict__ BtHW)
{
  int id = blockIdx.x * 256 + threadIdx.x;
  if (id < 262144){                       // BtP
    int jj = id >> 8, k = id & 255;
    float v = (jj < 512) ? W1[(size_t)k * 512 + jj] : W1[(size_t)(256 + k) * 512 + (jj - 512)];
    BtP[id] = f2bf(v);
  } else if (id < 294912){                // BtE pre-swizzled
    int i2 = id - 262144; int jj = i2 >> 6, c = i2 & 63;
    BtE[jj * 64 + (c ^ ((jj & 7) << 3))] = f2bf(W1[(size_t)(512 + c) * 512 + jj]);
  } else if (id < 425984){                // BtW2
    int i2 = id - 294912; int n = i2 >> 9, k = i2 & 511;
    BtW2[i2] = f2bf(W2[(size_t)k * 256 + n]);
  } else if (id < 688128){                // BtRZ
    int i2 = id - 425984; int col = i2 >> 9, k = i2 & 511;
    float v;
    if (col < 256) v = (k < 256) ? Wr[(size_t)k * 256 + col] : Ur[(size_t)(k - 256) * 256 + col];
    else { int c2 = col - 256; v = (k < 256) ? Wz[(size_t)k * 256 + c2] : Uz[(size_t)(k - 256) * 256 + c2]; }
    BtRZ[i2] = f2bf(v);
  } else if (id < 819200){                // BtHW
    int i2 = id - 688128; int col = i2 >> 9, k = i2 & 511;
    float v = (k < 256) ? Wh[(size_t)k * 256 + col] : Uh[(size_t)(k - 256) * 256 + col];
    BtHW[i2] = f2bf(v);
  }
}

// -------------------------------- readout ----------------------------------
__global__ __launch_bounds__(256)
void readout2(const float* __restrict__ g, const float* __restrict__ Wo,
              const float* __restrict__ bo, float* __restrict__ out){
  int t = threadIdx.x;
  int b = t >> 7, o = t & 127;
  float s = bo[o];
  for (int c = 0; c < 256; ++c) s += g[b * 256 + c] * Wo[c * 128 + o];
  out[b * 128 + o] = s;
}

// ===========================================================================
extern "C" void kernel_launch(void* const* d_in, const int* in_sizes, int n_in,
                              void* d_out, int out_size, void* d_ws, size_t ws_size,
                              hipStream_t stream)
{
  const float* ef  = (const float*)d_in[0];
  const float* W1  = (const float*)d_in[1];
  const float* b1  = (const float*)d_in[2];
  const float* W2  = (const float*)d_in[3];
  const float* b2  = (const float*)d_in[4];
  const float* Wr  = (const float*)d_in[5];
  const float* Ur  = (const float*)d_in[6];
  const float* br  = (const float*)d_in[7];
  const float* Wz  = (const float*)d_in[8];
  const float* Uz  = (const float*)d_in[9];
  const float* bz  = (const float*)d_in[10];
  const float* Wh  = (const float*)d_in[11];
  const float* Uh  = (const float*)d_in[12];
  const float* bh  = (const float*)d_in[13];
  const float* Wo  = (const float*)d_in[14];
  const float* bo  = (const float*)d_in[15];
  const int* esrc  = (const int*)d_in[16];
  const int* edst  = (const int*)d_in[17];

  char* base = (char*)d_ws;
  size_t off = 0;
  auto alloc = [&](size_t bytes) -> char* {
    off = (off + 255) & ~(size_t)255;
    char* p = base + off;
    off += bytes;
    return p;
  };
  float* h    = (float*)alloc((size_t)NB * 256 * 4);            // 16 MB
  float* m    = (float*)alloc((size_t)NB * 256 * 4);            // 16 MB
  short* P    = (short*)alloc((size_t)NB * 1024 * 2);           // 32 MB
  short* S    = (short*)alloc((size_t)NB * 512 * 2);            // 16 MB
  unsigned char* E1 = (unsigned char*)alloc((size_t)E_EDGES * 2 * MLPH); // 128 MiB
  short* BtP  = (short*)alloc(262144 * 2);
  short* BtE  = (short*)alloc(32768 * 2);
  short* BtW2 = (short*)alloc(131072 * 2);
  short* BtRZ = (short*)alloc(262144 * 2);
  short* BtHW = (short*)alloc(131072 * 2);
  int* counts = (int*)alloc(NNODES * 4);
  int* rs     = (int*)alloc((NNODES + 1) * 4);
  int* cursor = (int*)alloc(NNODES * 4);
  int* ceid   = (int*)alloc(E_EDGES * 4);
  int* csrc   = (int*)alloc(E_EDGES * 4);
  float* g    = (float*)alloc(512 * 4);
  // total ~216 MB < 256 MiB workspace

  dim3 blk(256);

  // ------------------------------- prep ----------------------------------
  hipMemsetAsync(g,  0, 512 * 4, stream);
  hipMemsetAsync(counts, 0, NNODES * 4, stream);
  prep_weights<<<3200, blk, 0, stream>>>(W1, W2, Wr, Ur, Wz, Uz, Wh, Uh,
                                         BtP, BtE, BtW2, BtRZ, BtHW);
  count_kernel<<<512, blk, 0, stream>>>(edst, counts);
  scan_kernel<<<1, 1024, 0, stream>>>(counts, rs, cursor);
  fill_kernel<<<512, blk, 0, stream>>>(edst, esrc, cursor, ceid, csrc);

  // E1 (fp8) computed ONCE — iteration-invariant
  e1_gemm<<<E_EDGES * 2 / 128, blk, 0, stream>>>(ef, BtE, E1, b1, ceid);

  // ----------------------------- iterations ------------------------------
  edge_kernel<false><<<NNODES, blk, 0, stream>>>(P, E1, csrc, rs, S);
  node_update<0><<<NB / RB, dim3(512), 0, stream>>>(S, P, m, h, g,
      BtW2, BtRZ, BtHW, BtP, counts, b2, br, bz, bh);

  edge_kernel<true><<<NNODES, blk, 0, stream>>>(P, E1, csrc, rs, S);
  node_update<1><<<NB / RB, dim3(512), 0, stream>>>(S, P, m, h, g,
      BtW2, BtRZ, BtHW, BtP, counts, b2, br, bz, bh);

  edge_kernel<true><<<NNODES, blk, 0, stream>>>(P, E1, csrc, rs, S);
  node_update<2><<<NB / RB, dim3(512), 0, stream>>>(S, P, m, h, g,
      BtW2, BtRZ, BtHW, BtP, counts, b2, br, bz, bh);

  // ------------------------------ readout --------------------------------
  readout2<<<1, blk, 0, stream>>>(g, Wo, bo, (float*)d_out);
}